// Round 3
// baseline (250.452 us; speedup 1.0000x reference)
//
#include <hip/hip_runtime.h>

// CARAFE: x(8,256,64,64) fp32
//   -> conv1x1 (256->64) -> comp bf16 NHWC [32768][64]
//   -> conv3x3 (64->100) as bf16 MFMA GEMM (M=32768, N=112pad, K=576) + fused softmax
//   -> reassembly (row-shuffle) -> out(8,256,128,128) fp32
// K=5, G=1, S=2.  mask layout: [pixel][n] with n = 4*j + sp (natural order).

#define CI 256

typedef __attribute__((ext_vector_type(8))) short bf16x8;
typedef __attribute__((ext_vector_type(4))) float f32x4;

__device__ inline unsigned short f2bf(float f) {
    unsigned u = __float_as_uint(f);
    unsigned r = (u + 0x7FFF + ((u >> 16) & 1)) >> 16;
    return (unsigned short)r;
}

// ---------------- kernel 0: weight prep ----------------
__global__ __launch_bounds__(256) void prep_weights(const float* __restrict__ w_comp,
                                                    const float* __restrict__ w_enc,
                                                    float* __restrict__ wT1,
                                                    unsigned short* __restrict__ Bp,
                                                    float* __restrict__ zp) {
    int i = blockIdx.x * 256 + threadIdx.x;
    if (i < 64) zp[i] = 0.f;
    if (i < 256 * 64) {
        int c = i >> 6, o = i & 63;
        wT1[i] = w_comp[o * 256 + c];
    }
    if (i < 72 * 112 * 8) {
        int j = i & 7;
        int n = (i >> 3) % 112;
        int g = i / (112 * 8);
        int k = g * 8 + j;
        int tap = k >> 6;
        int c = k & 63;
        float v = (n < 100) ? w_enc[n * 576 + c * 9 + tap] : 0.f;
        Bp[i] = f2bf(v);
    }
}

// ---------------- kernel 1: 1x1 conv (256 -> 64), comp stored bf16 NHWC ----------------
__global__ __launch_bounds__(256) void conv1x1(const float* __restrict__ x,
                                               const float* __restrict__ wT1,
                                               const float* __restrict__ b_comp,
                                               unsigned short* __restrict__ comp) {
    int w  = threadIdx.x & 63;
    int og = __builtin_amdgcn_readfirstlane(threadIdx.x >> 6);  // 0..3, wave-uniform
    const float* xp = x + ((size_t)(blockIdx.x >> 6) * CI) * 4096 + (blockIdx.x & 63) * 64 + w;
    const float* wp = wT1 + og * 16;

    float acc[16];
#pragma unroll
    for (int k = 0; k < 16; k++) acc[k] = 0.f;

#pragma unroll 4
    for (int c = 0; c < CI; c++) {
        float v = xp[(size_t)c * 4096];
#pragma unroll
        for (int k = 0; k < 16; k++) acc[k] += wp[c * 64 + k] * v;
    }

    unsigned short* cp = comp + ((size_t)(blockIdx.x * 64 + w)) * 64 + og * 16;
    unsigned vals[8];
#pragma unroll
    for (int q = 0; q < 8; q++) {
        unsigned lo = f2bf(acc[2 * q]     + b_comp[og * 16 + 2 * q]);
        unsigned hi = f2bf(acc[2 * q + 1] + b_comp[og * 16 + 2 * q + 1]);
        vals[q] = lo | (hi << 16);
    }
    reinterpret_cast<uint4*>(cp)[0] = uint4{vals[0], vals[1], vals[2], vals[3]};
    reinterpret_cast<uint4*>(cp)[1] = uint4{vals[4], vals[5], vals[6], vals[7]};
}

// ---------------- kernel 2: 3x3 conv as bf16 MFMA GEMM + fused softmax ----------------
// 1 wave/block. Wave: 32 pixels (2 M-tiles) x 112 outputs (7 N-tiles), K=576 in 18 steps.
__global__ __launch_bounds__(64) void conv3x3_mfma(const unsigned short* __restrict__ comp,
                                                   const unsigned short* __restrict__ Bp,
                                                   const float* __restrict__ b_enc,
                                                   const float* __restrict__ zp,
                                                   float* __restrict__ mask) {
    int l   = threadIdx.x;
    int c16 = l & 15;
    int lq  = l >> 4;
    int P0  = blockIdx.x * 32;
    int nimg = P0 >> 12;
    int h    = (P0 & 4095) >> 6;
    int w0   = P0 & 63;          // 0 or 32

    const char* cbase = (const char*)(comp + (size_t)nimg * 4096 * 64);
    const char* zpb   = (const char*)zp;
    int koff = lq * 16;          // (lq*8 bf16)*2B

    f32x4 acc[2][7];
#pragma unroll
    for (int mt = 0; mt < 2; mt++)
#pragma unroll
        for (int nt = 0; nt < 7; nt++) acc[mt][nt] = f32x4{0.f, 0.f, 0.f, 0.f};

    const char* bbase = (const char*)Bp + (lq * 112 + c16) * 16;

    int wf0 = w0 + c16;       // mt=0 pixel w
    int wf1 = wf0 + 16;       // mt=1 pixel w

#pragma unroll
    for (int tap = 0; tap < 9; tap++) {
        int dy = tap / 3 - 1, dx = tap % 3 - 1;
        int hh = h + dy;
        bool vy = (unsigned)hh < 64u;
        int ww0 = wf0 + dx, ww1 = wf1 + dx;
        const char* ap0 = (vy && (unsigned)ww0 < 64u) ? cbase + (hh * 64 + ww0) * 128 : zpb;
        const char* ap1 = (vy && (unsigned)ww1 < 64u) ? cbase + (hh * 64 + ww1) * 128 : zpb;
#pragma unroll
        for (int half = 0; half < 2; half++) {
            int s = tap * 2 + half;
            bf16x8 a0 = *(const bf16x8*)(ap0 + koff + half * 64);
            bf16x8 a1 = *(const bf16x8*)(ap1 + koff + half * 64);
            const char* bptr = bbase + s * 7168;
            bf16x8 bf[7];
#pragma unroll
            for (int nt = 0; nt < 7; nt++) bf[nt] = *(const bf16x8*)(bptr + nt * 256);
#pragma unroll
            for (int nt = 0; nt < 7; nt++) {
                acc[0][nt] = __builtin_amdgcn_mfma_f32_16x16x32_bf16(a0, bf[nt], acc[0][nt], 0, 0, 0);
                acc[1][nt] = __builtin_amdgcn_mfma_f32_16x16x32_bf16(a1, bf[nt], acc[1][nt], 0, 0, 0);
            }
        }
    }

    // bias + fused softmax.  n = nt*16+c16 = 4j+sp; group (pixel,sp) = lanes c16^{4,8,12}.
    float bias[7];
#pragma unroll
    for (int nt = 0; nt < 7; nt++) {
        int n = nt * 16 + c16;
        bias[nt] = (n < 100) ? b_enc[n] : 0.f;
    }
    int nvalid = (c16 < 4) ? 7 : 6;

#pragma unroll
    for (int mt = 0; mt < 2; mt++) {
#pragma unroll
        for (int r = 0; r < 4; r++) {
            float v[7];
#pragma unroll
            for (int nt = 0; nt < 7; nt++) v[nt] = acc[mt][nt][r] + bias[nt];
            float m = v[0];
#pragma unroll
            for (int nt = 1; nt < 7; nt++) if (nt < nvalid) m = fmaxf(m, v[nt]);
            m = fmaxf(m, __shfl_xor(m, 4));
            m = fmaxf(m, __shfl_xor(m, 8));
            float e[7];
            float s = 0.f;
#pragma unroll
            for (int nt = 0; nt < 7; nt++) {
                e[nt] = (nt < nvalid) ? __expf(v[nt] - m) : 0.f;
                s += e[nt];
            }
            s += __shfl_xor(s, 4);
            s += __shfl_xor(s, 8);
            float inv = 1.f / s;
            int pixel = P0 + mt * 16 + lq * 4 + r;
            float* mp = mask + (size_t)pixel * 100;
            // n-order store: 16-lane contiguous runs
#pragma unroll
            for (int nt = 0; nt < 7; nt++) if (nt < nvalid) mp[nt * 16 + c16] = e[nt] * inv;
        }
    }
}

// ---------------- kernel 3: reassembly (row-shuffle) ----------------
// lane = w (full row per wave). Per channel: 5 coalesced row loads; dx taps via
// ds_bpermute lane shifts; boundary zeros folded into msk.
__global__ __launch_bounds__(256, 4) void reassemble(const float* __restrict__ x,
                                                     const float* __restrict__ mask,
                                                     float* __restrict__ out) {
    int lane = threadIdx.x & 63;       // = w
    int cq   = threadIdx.x >> 6;       // 0..3, wave-uniform
    int b    = blockIdx.x;
    int h    = b & 63;
    int rest = b >> 6;                 // n*8 + cgb
    int cgb  = rest & 7;
    int n    = rest >> 3;
    int c0   = cgb * 32 + cq * 8;

    int pixel = (n * 64 + h) * 64 + lane;
    const float4* mp4 = reinterpret_cast<const float4*>(mask + (size_t)pixel * 100);

    int   yy[5];
    float vmy[5], vmx[5];
#pragma unroll
    for (int d = 0; d < 5; d++) {
        int y  = h + d - 2;
        int xc = lane + d - 2;
        yy[d]  = min(max(y, 0), 63) * 64;
        vmy[d] = ((unsigned)y  < 64u) ? 1.f : 0.f;
        vmx[d] = ((unsigned)xc < 64u) ? 1.f : 0.f;
    }

    // msk[j] = (sp0..sp3 weights for tap j) * boundary mask
    float4 msk[25];
#pragma unroll
    for (int j = 0; j < 25; j++) {
        float4 v = mp4[j];
        float  f = vmy[j / 5] * vmx[j % 5];
        msk[j] = make_float4(v.x * f, v.y * f, v.z * f, v.w * f);
    }

    int idxm2 = ((lane - 2) & 63) << 2;
    int idxm1 = ((lane - 1) & 63) << 2;
    int idxp1 = ((lane + 1) & 63) << 2;
    int idxp2 = ((lane + 2) & 63) << 2;

    const float* xbase = x + ((size_t)(n * CI + c0)) * 4096 + lane;
    float*       obase = out + ((size_t)(n * CI + c0) * 128 + 2 * h) * 128 + 2 * lane;

    for (int cc = 0; cc < 8; cc++) {
        const float* xc = xbase + (size_t)cc * 4096;
        float rowv[5];
#pragma unroll
        for (int d = 0; d < 5; d++) rowv[d] = xc[yy[d]];

        float a0 = 0.f, a1 = 0.f, a2 = 0.f, a3 = 0.f;
#pragma unroll
        for (int d = 0; d < 5; d++) {
            float vc  = rowv[d];
            int   vi  = __float_as_int(vc);
            float vm2 = __int_as_float(__builtin_amdgcn_ds_bpermute(idxm2, vi));
            float vm1 = __int_as_float(__builtin_amdgcn_ds_bpermute(idxm1, vi));
            float vp1 = __int_as_float(__builtin_amdgcn_ds_bpermute(idxp1, vi));
            float vp2 = __int_as_float(__builtin_amdgcn_ds_bpermute(idxp2, vi));
            float4 m0 = msk[d * 5 + 0];
            float4 m1 = msk[d * 5 + 1];
            float4 m2 = msk[d * 5 + 2];
            float4 m3 = msk[d * 5 + 3];
            float4 m4 = msk[d * 5 + 4];
            a0 += m0.x * vm2; a1 += m0.y * vm2; a2 += m0.z * vm2; a3 += m0.w * vm2;
            a0 += m1.x * vm1; a1 += m1.y * vm1; a2 += m1.z * vm1; a3 += m1.w * vm1;
            a0 += m2.x * vc;  a1 += m2.y * vc;  a2 += m2.z * vc;  a3 += m2.w * vc;
            a0 += m3.x * vp1; a1 += m3.y * vp1; a2 += m3.z * vp1; a3 += m3.w * vp1;
            a0 += m4.x * vp2; a1 += m4.y * vp2; a2 += m4.z * vp2; a3 += m4.w * vp2;
        }
        float* op = obase + cc * 16384;
        reinterpret_cast<float2*>(op)[0]       = make_float2(a0, a1);
        reinterpret_cast<float2*>(op + 128)[0] = make_float2(a2, a3);
    }
}

extern "C" void kernel_launch(void* const* d_in, const int* in_sizes, int n_in,
                              void* d_out, int out_size, void* d_ws, size_t ws_size,
                              hipStream_t stream) {
    const float* x      = (const float*)d_in[0];
    const float* w_comp = (const float*)d_in[1];
    const float* b_comp = (const float*)d_in[2];
    const float* w_enc  = (const float*)d_in[3];
    const float* b_enc  = (const float*)d_in[4];
    float* out = (float*)d_out;

    // workspace layout (bytes)
    char* ws = (char*)d_ws;
    float*          zp   = (float*)(ws + 0);                 // 256 B zeros
    float*          wT1  = (float*)(ws + 256);               // 64 KB
    unsigned short* Bp   = (unsigned short*)(ws + 65792);    // 129024 B
    unsigned short* comp = (unsigned short*)(ws + 194816);   // 4 MB
    float*          mask = (float*)(ws + 4389120);           // 13.1 MB
    // total ~17.5 MB

    prep_weights<<<252, 256, 0, stream>>>(w_comp, w_enc, wT1, Bp, zp);
    conv1x1<<<512, 256, 0, stream>>>(x, wT1, b_comp, comp);
    conv3x3_mfma<<<1024, 64, 0, stream>>>(comp, Bp, b_enc, zp, mask);
    reassemble<<<4096, 256, 0, stream>>>(x, mask, out);
}

// Round 4
// 149.622 us; speedup vs baseline: 1.6739x; 1.6739x over previous
//
#include <hip/hip_runtime.h>

// CARAFE: x(8,256,64,64) fp32
//   -> conv1x1 (256->64) -> comp bf16 NHWC [32768][64]
//   -> conv3x3 (64->100) as bf16 MFMA GEMM (M=32768, N=112pad, K=576) + fused softmax
//   -> reassembly (row-shuffle, pipelined, XCD-swizzled) -> out(8,256,128,128) fp32
// K=5, G=1, S=2.  mask layout: [pixel][n] with n = 4*j + sp (natural order).

#define CI 256

typedef __attribute__((ext_vector_type(8))) short bf16x8;
typedef __attribute__((ext_vector_type(4))) float f32x4;

__device__ inline unsigned short f2bf(float f) {
    unsigned u = __float_as_uint(f);
    unsigned r = (u + 0x7FFF + ((u >> 16) & 1)) >> 16;
    return (unsigned short)r;
}

// ---------------- kernel 0: weight prep ----------------
__global__ __launch_bounds__(256) void prep_weights(const float* __restrict__ w_comp,
                                                    const float* __restrict__ w_enc,
                                                    float* __restrict__ wT1,
                                                    unsigned short* __restrict__ Bp,
                                                    float* __restrict__ zp) {
    int i = blockIdx.x * 256 + threadIdx.x;
    if (i < 64) zp[i] = 0.f;
    if (i < 256 * 64) {
        int c = i >> 6, o = i & 63;
        wT1[i] = w_comp[o * 256 + c];
    }
    if (i < 72 * 112 * 8) {
        int j = i & 7;
        int n = (i >> 3) % 112;
        int g = i / (112 * 8);
        int k = g * 8 + j;
        int tap = k >> 6;
        int c = k & 63;
        float v = (n < 100) ? w_enc[n * 576 + c * 9 + tap] : 0.f;
        Bp[i] = f2bf(v);
    }
}

// ---------------- kernel 1: 1x1 conv (256 -> 64), comp stored bf16 NHWC ----------------
__global__ __launch_bounds__(256) void conv1x1(const float* __restrict__ x,
                                               const float* __restrict__ wT1,
                                               const float* __restrict__ b_comp,
                                               unsigned short* __restrict__ comp) {
    int w  = threadIdx.x & 63;
    int og = __builtin_amdgcn_readfirstlane(threadIdx.x >> 6);  // 0..3, wave-uniform
    const float* xp = x + ((size_t)(blockIdx.x >> 6) * CI) * 4096 + (blockIdx.x & 63) * 64 + w;
    const float* wp = wT1 + og * 16;

    float acc[16];
#pragma unroll
    for (int k = 0; k < 16; k++) acc[k] = 0.f;

#pragma unroll 4
    for (int c = 0; c < CI; c++) {
        float v = xp[(size_t)c * 4096];
#pragma unroll
        for (int k = 0; k < 16; k++) acc[k] += wp[c * 64 + k] * v;
    }

    unsigned short* cp = comp + ((size_t)(blockIdx.x * 64 + w)) * 64 + og * 16;
    unsigned vals[8];
#pragma unroll
    for (int q = 0; q < 8; q++) {
        unsigned lo = f2bf(acc[2 * q]     + b_comp[og * 16 + 2 * q]);
        unsigned hi = f2bf(acc[2 * q + 1] + b_comp[og * 16 + 2 * q + 1]);
        vals[q] = lo | (hi << 16);
    }
    reinterpret_cast<uint4*>(cp)[0] = uint4{vals[0], vals[1], vals[2], vals[3]};
    reinterpret_cast<uint4*>(cp)[1] = uint4{vals[4], vals[5], vals[6], vals[7]};
}

// ---------------- kernel 2: 3x3 conv as bf16 MFMA GEMM + fused softmax ----------------
// 1 wave/block. Wave: 32 pixels (2 M-tiles) x 112 outputs (7 N-tiles), K=576 in 18 steps.
__global__ __launch_bounds__(64) void conv3x3_mfma(const unsigned short* __restrict__ comp,
                                                   const unsigned short* __restrict__ Bp,
                                                   const float* __restrict__ b_enc,
                                                   const float* __restrict__ zp,
                                                   float* __restrict__ mask) {
    int l   = threadIdx.x;
    int c16 = l & 15;
    int lq  = l >> 4;
    int P0  = blockIdx.x * 32;
    int nimg = P0 >> 12;
    int h    = (P0 & 4095) >> 6;
    int w0   = P0 & 63;          // 0 or 32

    const char* cbase = (const char*)(comp + (size_t)nimg * 4096 * 64);
    const char* zpb   = (const char*)zp;
    int koff = lq * 16;          // (lq*8 bf16)*2B

    f32x4 acc[2][7];
#pragma unroll
    for (int mt = 0; mt < 2; mt++)
#pragma unroll
        for (int nt = 0; nt < 7; nt++) acc[mt][nt] = f32x4{0.f, 0.f, 0.f, 0.f};

    const char* bbase = (const char*)Bp + (lq * 112 + c16) * 16;

    int wf0 = w0 + c16;       // mt=0 pixel w
    int wf1 = wf0 + 16;       // mt=1 pixel w

#pragma unroll
    for (int tap = 0; tap < 9; tap++) {
        int dy = tap / 3 - 1, dx = tap % 3 - 1;
        int hh = h + dy;
        bool vy = (unsigned)hh < 64u;
        int ww0 = wf0 + dx, ww1 = wf1 + dx;
        const char* ap0 = (vy && (unsigned)ww0 < 64u) ? cbase + (hh * 64 + ww0) * 128 : zpb;
        const char* ap1 = (vy && (unsigned)ww1 < 64u) ? cbase + (hh * 64 + ww1) * 128 : zpb;
#pragma unroll
        for (int half = 0; half < 2; half++) {
            int s = tap * 2 + half;
            bf16x8 a0 = *(const bf16x8*)(ap0 + koff + half * 64);
            bf16x8 a1 = *(const bf16x8*)(ap1 + koff + half * 64);
            const char* bptr = bbase + s * 7168;
            bf16x8 bf[7];
#pragma unroll
            for (int nt = 0; nt < 7; nt++) bf[nt] = *(const bf16x8*)(bptr + nt * 256);
#pragma unroll
            for (int nt = 0; nt < 7; nt++) {
                acc[0][nt] = __builtin_amdgcn_mfma_f32_16x16x32_bf16(a0, bf[nt], acc[0][nt], 0, 0, 0);
                acc[1][nt] = __builtin_amdgcn_mfma_f32_16x16x32_bf16(a1, bf[nt], acc[1][nt], 0, 0, 0);
            }
        }
    }

    // bias + fused softmax.  n = nt*16+c16 = 4j+sp; group (pixel,sp) = lanes c16^{4,8,12}.
    float bias[7];
#pragma unroll
    for (int nt = 0; nt < 7; nt++) {
        int n = nt * 16 + c16;
        bias[nt] = (n < 100) ? b_enc[n] : 0.f;
    }
    int nvalid = (c16 < 4) ? 7 : 6;

#pragma unroll
    for (int mt = 0; mt < 2; mt++) {
#pragma unroll
        for (int r = 0; r < 4; r++) {
            float v[7];
#pragma unroll
            for (int nt = 0; nt < 7; nt++) v[nt] = acc[mt][nt][r] + bias[nt];
            float m = v[0];
#pragma unroll
            for (int nt = 1; nt < 7; nt++) if (nt < nvalid) m = fmaxf(m, v[nt]);
            m = fmaxf(m, __shfl_xor(m, 4));
            m = fmaxf(m, __shfl_xor(m, 8));
            float e[7];
            float s = 0.f;
#pragma unroll
            for (int nt = 0; nt < 7; nt++) {
                e[nt] = (nt < nvalid) ? __expf(v[nt] - m) : 0.f;
                s += e[nt];
            }
            s += __shfl_xor(s, 4);
            s += __shfl_xor(s, 8);
            float inv = 1.f / s;
            int pixel = P0 + mt * 16 + lq * 4 + r;
            float* mp = mask + (size_t)pixel * 100;
#pragma unroll
            for (int nt = 0; nt < 7; nt++) if (nt < nvalid) mp[nt * 16 + c16] = e[nt] * inv;
        }
    }
}

// ---------------- kernel 3: reassembly (row-shuffle, pipelined, XCD-swizzled) ----------------
// lane = w (full row per wave). Per channel: 5 coalesced row loads (prefetched one
// channel ahead); dx taps via ds_bpermute; boundary zeros folded into msk.
// XCD swizzle: bs=(b&7)*512+(b>>3) -> each XCD owns one image n, all cgb, all h
// contiguously, so dy-halo rows (5x) and mask (8x across cgb) are same-L2 reuse.
__global__ __launch_bounds__(256) void reassemble(const float* __restrict__ x,
                                                  const float* __restrict__ mask,
                                                  float* __restrict__ out) {
    int lane = threadIdx.x & 63;       // = w
    int cq   = threadIdx.x >> 6;       // 0..3, wave-uniform
    int b    = blockIdx.x;
    int bs   = (b & 7) * 512 + (b >> 3);   // bijective: 4096 = 8 * 512
    int h    = bs & 63;
    int rest = bs >> 6;                // n*8 + cgb
    int cgb  = rest & 7;
    int n    = rest >> 3;
    int c0   = cgb * 32 + cq * 8;

    int pixel = (n * 64 + h) * 64 + lane;
    const float4* mp4 = reinterpret_cast<const float4*>(mask + (size_t)pixel * 100);

    int   yy[5];
    float vmy[5], vmx[5];
#pragma unroll
    for (int d = 0; d < 5; d++) {
        int y  = h + d - 2;
        int xc = lane + d - 2;
        yy[d]  = min(max(y, 0), 63) * 64;
        vmy[d] = ((unsigned)y  < 64u) ? 1.f : 0.f;
        vmx[d] = ((unsigned)xc < 64u) ? 1.f : 0.f;
    }

    // msk[j] = (sp0..sp3 weights for tap j) * boundary mask
    float4 msk[25];
#pragma unroll
    for (int j = 0; j < 25; j++) {
        float4 v = mp4[j];
        float  f = vmy[j / 5] * vmx[j % 5];
        msk[j] = make_float4(v.x * f, v.y * f, v.z * f, v.w * f);
    }

    int idxm2 = ((lane - 2) & 63) << 2;
    int idxm1 = ((lane - 1) & 63) << 2;
    int idxp1 = ((lane + 1) & 63) << 2;
    int idxp2 = ((lane + 2) & 63) << 2;

    const float* xbase = x + ((size_t)(n * CI + c0)) * 4096 + lane;
    float*       obase = out + ((size_t)(n * CI + c0) * 128 + 2 * h) * 128 + 2 * lane;

    float rowv[5];
#pragma unroll
    for (int d = 0; d < 5; d++) rowv[d] = xbase[yy[d]];

    for (int cc = 0; cc < 8; cc++) {
        // prefetch next channel's rows (safe addr clamp for last iter)
        const float* xn = xbase + (size_t)((cc < 7) ? (cc + 1) : 0) * 4096;
        float rown[5];
#pragma unroll
        for (int d = 0; d < 5; d++) rown[d] = xn[yy[d]];

        float a0 = 0.f, a1 = 0.f, a2 = 0.f, a3 = 0.f;
#pragma unroll
        for (int d = 0; d < 5; d++) {
            float vc  = rowv[d];
            int   vi  = __float_as_int(vc);
            float vm2 = __int_as_float(__builtin_amdgcn_ds_bpermute(idxm2, vi));
            float vm1 = __int_as_float(__builtin_amdgcn_ds_bpermute(idxm1, vi));
            float vp1 = __int_as_float(__builtin_amdgcn_ds_bpermute(idxp1, vi));
            float vp2 = __int_as_float(__builtin_amdgcn_ds_bpermute(idxp2, vi));
            float4 m0 = msk[d * 5 + 0];
            float4 m1 = msk[d * 5 + 1];
            float4 m2 = msk[d * 5 + 2];
            float4 m3 = msk[d * 5 + 3];
            float4 m4 = msk[d * 5 + 4];
            a0 += m0.x * vm2; a1 += m0.y * vm2; a2 += m0.z * vm2; a3 += m0.w * vm2;
            a0 += m1.x * vm1; a1 += m1.y * vm1; a2 += m1.z * vm1; a3 += m1.w * vm1;
            a0 += m2.x * vc;  a1 += m2.y * vc;  a2 += m2.z * vc;  a3 += m2.w * vc;
            a0 += m3.x * vp1; a1 += m3.y * vp1; a2 += m3.z * vp1; a3 += m3.w * vp1;
            a0 += m4.x * vp2; a1 += m4.y * vp2; a2 += m4.z * vp2; a3 += m4.w * vp2;
        }
        float* op = obase + cc * 16384;
        reinterpret_cast<float2*>(op)[0]       = make_float2(a0, a1);
        reinterpret_cast<float2*>(op + 128)[0] = make_float2(a2, a3);

#pragma unroll
        for (int d = 0; d < 5; d++) rowv[d] = rown[d];
    }
}

extern "C" void kernel_launch(void* const* d_in, const int* in_sizes, int n_in,
                              void* d_out, int out_size, void* d_ws, size_t ws_size,
                              hipStream_t stream) {
    const float* x      = (const float*)d_in[0];
    const float* w_comp = (const float*)d_in[1];
    const float* b_comp = (const float*)d_in[2];
    const float* w_enc  = (const float*)d_in[3];
    const float* b_enc  = (const float*)d_in[4];
    float* out = (float*)d_out;

    // workspace layout (bytes)
    char* ws = (char*)d_ws;
    float*          zp   = (float*)(ws + 0);                 // 256 B zeros
    float*          wT1  = (float*)(ws + 256);               // 64 KB
    unsigned short* Bp   = (unsigned short*)(ws + 65792);    // 129024 B
    unsigned short* comp = (unsigned short*)(ws + 194816);   // 4 MB
    float*          mask = (float*)(ws + 4389120);           // 13.1 MB
    // total ~17.5 MB

    prep_weights<<<252, 256, 0, stream>>>(w_comp, w_enc, wT1, Bp, zp);
    conv1x1<<<512, 256, 0, stream>>>(x, wT1, b_comp, comp);
    conv3x3_mfma<<<1024, 64, 0, stream>>>(comp, Bp, b_enc, zp, mask);
    reassemble<<<4096, 256, 0, stream>>>(x, mask, out);
}

// Round 5
// 144.483 us; speedup vs baseline: 1.7334x; 1.0356x over previous
//
#include <hip/hip_runtime.h>

// CARAFE: x(8,256,64,64) fp32
//   -> conv1x1 (256->64) -> comp bf16 NHWC [32768][64]
//   -> conv3x3 (64->100) as bf16 MFMA GEMM (M=32768, N=112pad, K=576) + fused softmax
//   -> reassembly (row-shuffle, pipelined, XCD-swizzled) -> out(8,256,128,128) fp32
// K=5, G=1, S=2.
// mask layout (TRANSPOSED): maskT[nimg][h][n=4j+sp][w]  -> reassemble reads coalesced.

#define CI 256

typedef __attribute__((ext_vector_type(8))) short bf16x8;
typedef __attribute__((ext_vector_type(4))) float f32x4;

__device__ inline unsigned short f2bf(float f) {
    unsigned u = __float_as_uint(f);
    unsigned r = (u + 0x7FFF + ((u >> 16) & 1)) >> 16;
    return (unsigned short)r;
}

// ---------------- kernel 0: weight prep ----------------
__global__ __launch_bounds__(256) void prep_weights(const float* __restrict__ w_comp,
                                                    const float* __restrict__ w_enc,
                                                    float* __restrict__ wT1,
                                                    unsigned short* __restrict__ Bp,
                                                    float* __restrict__ zp) {
    int i = blockIdx.x * 256 + threadIdx.x;
    if (i < 64) zp[i] = 0.f;
    if (i < 256 * 64) {
        int c = i >> 6, o = i & 63;
        wT1[i] = w_comp[o * 256 + c];
    }
    if (i < 72 * 112 * 8) {
        int j = i & 7;
        int n = (i >> 3) % 112;
        int g = i / (112 * 8);
        int k = g * 8 + j;
        int tap = k >> 6;
        int c = k & 63;
        float v = (n < 100) ? w_enc[n * 576 + c * 9 + tap] : 0.f;
        Bp[i] = f2bf(v);
    }
}

// ---------------- kernel 1: 1x1 conv (256 -> 64), comp stored bf16 NHWC ----------------
__global__ __launch_bounds__(256) void conv1x1(const float* __restrict__ x,
                                               const float* __restrict__ wT1,
                                               const float* __restrict__ b_comp,
                                               unsigned short* __restrict__ comp) {
    int w  = threadIdx.x & 63;
    int og = __builtin_amdgcn_readfirstlane(threadIdx.x >> 6);  // 0..3, wave-uniform
    const float* xp = x + ((size_t)(blockIdx.x >> 6) * CI) * 4096 + (blockIdx.x & 63) * 64 + w;
    const float* wp = wT1 + og * 16;

    float acc[16];
#pragma unroll
    for (int k = 0; k < 16; k++) acc[k] = 0.f;

#pragma unroll 4
    for (int c = 0; c < CI; c++) {
        float v = xp[(size_t)c * 4096];
#pragma unroll
        for (int k = 0; k < 16; k++) acc[k] += wp[c * 64 + k] * v;
    }

    unsigned short* cp = comp + ((size_t)(blockIdx.x * 64 + w)) * 64 + og * 16;
    unsigned vals[8];
#pragma unroll
    for (int q = 0; q < 8; q++) {
        unsigned lo = f2bf(acc[2 * q]     + b_comp[og * 16 + 2 * q]);
        unsigned hi = f2bf(acc[2 * q + 1] + b_comp[og * 16 + 2 * q + 1]);
        vals[q] = lo | (hi << 16);
    }
    reinterpret_cast<uint4*>(cp)[0] = uint4{vals[0], vals[1], vals[2], vals[3]};
    reinterpret_cast<uint4*>(cp)[1] = uint4{vals[4], vals[5], vals[6], vals[7]};
}

// ---------------- kernel 2: 3x3 conv as bf16 MFMA GEMM + fused softmax ----------------
// 1 wave/block. Wave: 32 pixels (2 M-tiles) x 112 outputs (7 N-tiles), K=576 in 18 steps.
// Stores maskT[nimg][h][n][w].
__global__ __launch_bounds__(64) void conv3x3_mfma(const unsigned short* __restrict__ comp,
                                                   const unsigned short* __restrict__ Bp,
                                                   const float* __restrict__ b_enc,
                                                   const float* __restrict__ zp,
                                                   float* __restrict__ maskT) {
    int l   = threadIdx.x;
    int c16 = l & 15;
    int lq  = l >> 4;
    int P0  = blockIdx.x * 32;
    int nimg = P0 >> 12;
    int h    = (P0 & 4095) >> 6;
    int w0   = P0 & 63;          // 0 or 32

    const char* cbase = (const char*)(comp + (size_t)nimg * 4096 * 64);
    const char* zpb   = (const char*)zp;
    int koff = lq * 16;          // (lq*8 bf16)*2B

    f32x4 acc[2][7];
#pragma unroll
    for (int mt = 0; mt < 2; mt++)
#pragma unroll
        for (int nt = 0; nt < 7; nt++) acc[mt][nt] = f32x4{0.f, 0.f, 0.f, 0.f};

    const char* bbase = (const char*)Bp + (lq * 112 + c16) * 16;

    int wf0 = w0 + c16;       // mt=0 pixel w
    int wf1 = wf0 + 16;       // mt=1 pixel w

#pragma unroll
    for (int tap = 0; tap < 9; tap++) {
        int dy = tap / 3 - 1, dx = tap % 3 - 1;
        int hh = h + dy;
        bool vy = (unsigned)hh < 64u;
        int ww0 = wf0 + dx, ww1 = wf1 + dx;
        const char* ap0 = (vy && (unsigned)ww0 < 64u) ? cbase + (hh * 64 + ww0) * 128 : zpb;
        const char* ap1 = (vy && (unsigned)ww1 < 64u) ? cbase + (hh * 64 + ww1) * 128 : zpb;
#pragma unroll
        for (int half = 0; half < 2; half++) {
            int s = tap * 2 + half;
            bf16x8 a0 = *(const bf16x8*)(ap0 + koff + half * 64);
            bf16x8 a1 = *(const bf16x8*)(ap1 + koff + half * 64);
            const char* bptr = bbase + s * 7168;
            bf16x8 bf[7];
#pragma unroll
            for (int nt = 0; nt < 7; nt++) bf[nt] = *(const bf16x8*)(bptr + nt * 256);
#pragma unroll
            for (int nt = 0; nt < 7; nt++) {
                acc[0][nt] = __builtin_amdgcn_mfma_f32_16x16x32_bf16(a0, bf[nt], acc[0][nt], 0, 0, 0);
                acc[1][nt] = __builtin_amdgcn_mfma_f32_16x16x32_bf16(a1, bf[nt], acc[1][nt], 0, 0, 0);
            }
        }
    }

    // bias + fused softmax.  n = nt*16+c16 = 4j+sp; group (pixel,sp) = lanes c16^{4,8,12}.
    float bias[7];
#pragma unroll
    for (int nt = 0; nt < 7; nt++) {
        int n = nt * 16 + c16;
        bias[nt] = (n < 100) ? b_enc[n] : 0.f;
    }
    int nvalid = (c16 < 4) ? 7 : 6;

    float* mbase = maskT + ((size_t)nimg * 64 + h) * 6400;

#pragma unroll
    for (int mt = 0; mt < 2; mt++) {
#pragma unroll
        for (int r = 0; r < 4; r++) {
            float v[7];
#pragma unroll
            for (int nt = 0; nt < 7; nt++) v[nt] = acc[mt][nt][r] + bias[nt];
            float m = v[0];
#pragma unroll
            for (int nt = 1; nt < 7; nt++) if (nt < nvalid) m = fmaxf(m, v[nt]);
            m = fmaxf(m, __shfl_xor(m, 4));
            m = fmaxf(m, __shfl_xor(m, 8));
            float e[7];
            float s = 0.f;
#pragma unroll
            for (int nt = 0; nt < 7; nt++) {
                e[nt] = (nt < nvalid) ? __expf(v[nt] - m) : 0.f;
                s += e[nt];
            }
            s += __shfl_xor(s, 4);
            s += __shfl_xor(s, 8);
            float inv = 1.f / s;
            int wpix = w0 + mt * 16 + lq * 4 + r;     // pixel's w
            float* mp = mbase + wpix;
#pragma unroll
            for (int nt = 0; nt < 7; nt++)
                if (nt < nvalid) mp[(nt * 16 + c16) * 64] = e[nt] * inv;
        }
    }
}

// ---------------- kernel 3: reassembly (row-shuffle, coalesced mask) ----------------
// lane = w. maskT read: mrow[n*64] is a fully coalesced 256B load per weight n.
// dx taps via ds_bpermute; boundary zeros folded into msk at load.
__global__ __launch_bounds__(256) void reassemble(const float* __restrict__ x,
                                                  const float* __restrict__ maskT,
                                                  float* __restrict__ out) {
    int lane = threadIdx.x & 63;       // = w
    int cq   = threadIdx.x >> 6;       // 0..3, wave-uniform
    int b    = blockIdx.x;
    int bs   = (b & 7) * 512 + (b >> 3);   // bijective: 4096 = 8 * 512
    int h    = bs & 63;
    int rest = bs >> 6;                // n*8 + cgb
    int cgb  = rest & 7;
    int n    = rest >> 3;
    int c0   = cgb * 32 + cq * 8;

    const float* mrow = maskT + ((size_t)n * 64 + h) * 6400 + lane;

    int   yy[5];
    float vmy[5], vmx[5];
#pragma unroll
    for (int d = 0; d < 5; d++) {
        int y  = h + d - 2;
        int xc = lane + d - 2;
        yy[d]  = min(max(y, 0), 63) * 64;
        vmy[d] = ((unsigned)y  < 64u) ? 1.f : 0.f;
        vmx[d] = ((unsigned)xc < 64u) ? 1.f : 0.f;
    }

    // msk[t*4+sp] = mask weight for tap t, subpixel sp, times boundary fold
    float msk[100];
#pragma unroll
    for (int t = 0; t < 25; t++) {
        float f = vmy[t / 5] * vmx[t % 5];
        msk[4 * t + 0] = mrow[(4 * t + 0) * 64] * f;
        msk[4 * t + 1] = mrow[(4 * t + 1) * 64] * f;
        msk[4 * t + 2] = mrow[(4 * t + 2) * 64] * f;
        msk[4 * t + 3] = mrow[(4 * t + 3) * 64] * f;
    }

    int idxm2 = ((lane - 2) & 63) << 2;
    int idxm1 = ((lane - 1) & 63) << 2;
    int idxp1 = ((lane + 1) & 63) << 2;
    int idxp2 = ((lane + 2) & 63) << 2;

    const float* xbase = x + ((size_t)(n * CI + c0)) * 4096 + lane;
    float*       obase = out + ((size_t)(n * CI + c0) * 128 + 2 * h) * 128 + 2 * lane;

    float rowv[5];
#pragma unroll
    for (int d = 0; d < 5; d++) rowv[d] = xbase[yy[d]];

    for (int cc = 0; cc < 8; cc++) {
        const float* xn = xbase + (size_t)((cc < 7) ? (cc + 1) : 0) * 4096;
        float rown[5];
#pragma unroll
        for (int d = 0; d < 5; d++) rown[d] = xn[yy[d]];

        float a0 = 0.f, a1 = 0.f, a2 = 0.f, a3 = 0.f;
#pragma unroll
        for (int d = 0; d < 5; d++) {
            float vc  = rowv[d];
            int   vi  = __float_as_int(vc);
            float vm2 = __int_as_float(__builtin_amdgcn_ds_bpermute(idxm2, vi));
            float vm1 = __int_as_float(__builtin_amdgcn_ds_bpermute(idxm1, vi));
            float vp1 = __int_as_float(__builtin_amdgcn_ds_bpermute(idxp1, vi));
            float vp2 = __int_as_float(__builtin_amdgcn_ds_bpermute(idxp2, vi));
            const float* mk = msk + d * 20;
            a0 += mk[0]  * vm2; a1 += mk[1]  * vm2; a2 += mk[2]  * vm2; a3 += mk[3]  * vm2;
            a0 += mk[4]  * vm1; a1 += mk[5]  * vm1; a2 += mk[6]  * vm1; a3 += mk[7]  * vm1;
            a0 += mk[8]  * vc;  a1 += mk[9]  * vc;  a2 += mk[10] * vc;  a3 += mk[11] * vc;
            a0 += mk[12] * vp1; a1 += mk[13] * vp1; a2 += mk[14] * vp1; a3 += mk[15] * vp1;
            a0 += mk[16] * vp2; a1 += mk[17] * vp2; a2 += mk[18] * vp2; a3 += mk[19] * vp2;
        }
        float* op = obase + cc * 16384;
        reinterpret_cast<float2*>(op)[0]       = make_float2(a0, a1);
        reinterpret_cast<float2*>(op + 128)[0] = make_float2(a2, a3);

#pragma unroll
        for (int d = 0; d < 5; d++) rowv[d] = rown[d];
    }
}

extern "C" void kernel_launch(void* const* d_in, const int* in_sizes, int n_in,
                              void* d_out, int out_size, void* d_ws, size_t ws_size,
                              hipStream_t stream) {
    const float* x      = (const float*)d_in[0];
    const float* w_comp = (const float*)d_in[1];
    const float* b_comp = (const float*)d_in[2];
    const float* w_enc  = (const float*)d_in[3];
    const float* b_enc  = (const float*)d_in[4];
    float* out = (float*)d_out;

    // workspace layout (bytes)
    char* ws = (char*)d_ws;
    float*          zp    = (float*)(ws + 0);                 // 256 B zeros
    float*          wT1   = (float*)(ws + 256);               // 64 KB
    unsigned short* Bp    = (unsigned short*)(ws + 65792);    // 129024 B
    unsigned short* comp  = (unsigned short*)(ws + 194816);   // 4 MB
    float*          maskT = (float*)(ws + 4389120);           // 8*64*100*64*4 = 13.1 MB
    // total ~17.5 MB

    prep_weights<<<252, 256, 0, stream>>>(w_comp, w_enc, wT1, Bp, zp);
    conv1x1<<<512, 256, 0, stream>>>(x, wT1, b_comp, comp);
    conv3x3_mfma<<<1024, 64, 0, stream>>>(comp, Bp, b_enc, zp, maskT);
    reassemble<<<4096, 256, 0, stream>>>(x, maskT, out);
}

// Round 6
// 127.738 us; speedup vs baseline: 1.9607x; 1.1311x over previous
//
#include <hip/hip_runtime.h>

// CARAFE: x(8,256,64,64) fp32
//   -> conv1x1 (256->64) -> comp bf16 NHWC [32768][64]
//   -> conv3x3 (64->100) as bf16 MFMA GEMM (M=32768, N=112pad, K=576) + fused softmax
//   -> reassembly (row-shuffle, sp-split, XCD-swizzled) -> out(8,256,128,128) fp32
// K=5, G=1, S=2.
// mask layout: maskT[nimg][h][n=4j+sp][w] -> both conv3x3 store and reassemble load coalesced.

#define CI 256

typedef __attribute__((ext_vector_type(8))) short bf16x8;
typedef __attribute__((ext_vector_type(4))) float f32x4;

__device__ inline unsigned short f2bf(float f) {
    unsigned u = __float_as_uint(f);
    unsigned r = (u + 0x7FFF + ((u >> 16) & 1)) >> 16;
    return (unsigned short)r;
}

// ---------------- kernel 0: weight prep ----------------
__global__ __launch_bounds__(256) void prep_weights(const float* __restrict__ w_comp,
                                                    const float* __restrict__ w_enc,
                                                    float* __restrict__ wT1,
                                                    unsigned short* __restrict__ Bp,
                                                    float* __restrict__ zp) {
    int i = blockIdx.x * 256 + threadIdx.x;
    if (i < 64) zp[i] = 0.f;
    if (i < 256 * 64) {
        int c = i >> 6, o = i & 63;
        wT1[i] = w_comp[o * 256 + c];
    }
    if (i < 72 * 112 * 8) {
        int j = i & 7;
        int n = (i >> 3) % 112;
        int g = i / (112 * 8);
        int k = g * 8 + j;
        int tap = k >> 6;
        int c = k & 63;
        float v = (n < 100) ? w_enc[n * 576 + c * 9 + tap] : 0.f;
        Bp[i] = f2bf(v);
    }
}

// ---------------- kernel 1: 1x1 conv (256 -> 64), comp stored bf16 NHWC ----------------
// block 256 = (64 w, 4 og). Each thread: 8 output channels. grid 1024 = spatial*2 halves.
// XCD swizzle: consecutive bs pairs (same x row, both halves) share an L2.
__global__ __launch_bounds__(256) void conv1x1(const float* __restrict__ x,
                                               const float* __restrict__ wT1,
                                               const float* __restrict__ b_comp,
                                               unsigned short* __restrict__ comp) {
    int w  = threadIdx.x & 63;
    int og = __builtin_amdgcn_readfirstlane(threadIdx.x >> 6);  // 0..3, wave-uniform
    int b  = blockIdx.x;
    int bs = (b & 7) * 128 + (b >> 3);   // bijective: 1024 = 8*128
    int half = bs & 1;
    int h    = (bs >> 1) & 63;
    int nimg = bs >> 7;
    int och0 = half * 32 + og * 8;

    const float* xp = x + ((size_t)nimg * CI) * 4096 + h * 64 + w;
    const float* wp = wT1 + och0;

    float acc[8];
#pragma unroll
    for (int k = 0; k < 8; k++) acc[k] = 0.f;

    for (int c = 0; c < CI; c += 8) {
        float v[8];
#pragma unroll
        for (int i = 0; i < 8; i++) v[i] = xp[(size_t)(c + i) * 4096];
#pragma unroll
        for (int i = 0; i < 8; i++) {
#pragma unroll
            for (int k = 0; k < 8; k++) acc[k] += wp[(c + i) * 64 + k] * v[i];
        }
    }

    unsigned short* cp = comp + ((size_t)((nimg * 64 + h) * 64 + w)) * 64 + och0;
    unsigned vals[4];
#pragma unroll
    for (int q = 0; q < 4; q++) {
        unsigned lo = f2bf(acc[2 * q]     + b_comp[och0 + 2 * q]);
        unsigned hi = f2bf(acc[2 * q + 1] + b_comp[och0 + 2 * q + 1]);
        vals[q] = lo | (hi << 16);
    }
    reinterpret_cast<uint4*>(cp)[0] = uint4{vals[0], vals[1], vals[2], vals[3]};
}

// ---------------- kernel 2: 3x3 conv as bf16 MFMA GEMM + fused softmax ----------------
// 1 wave/block. Wave: 32 pixels (2 M-tiles) x 112 outputs (7 N-tiles), K=576 in 18 steps.
// Stores maskT[nimg][h][n][w]. XCD swizzle: each XCD owns one image (comp slice L2-resident).
__global__ __launch_bounds__(64) void conv3x3_mfma(const unsigned short* __restrict__ comp,
                                                   const unsigned short* __restrict__ Bp,
                                                   const float* __restrict__ b_enc,
                                                   const float* __restrict__ zp,
                                                   float* __restrict__ maskT) {
    int l   = threadIdx.x;
    int c16 = l & 15;
    int lq  = l >> 4;
    int b   = blockIdx.x;
    int bs  = (b & 7) * 128 + (b >> 3);   // bijective: 1024 = 8*128
    int P0  = bs * 32;
    int nimg = P0 >> 12;
    int h    = (P0 & 4095) >> 6;
    int w0   = P0 & 63;          // 0 or 32

    const char* cbase = (const char*)(comp + (size_t)nimg * 4096 * 64);
    const char* zpb   = (const char*)zp;
    int koff = lq * 16;          // (lq*8 bf16)*2B

    f32x4 acc[2][7];
#pragma unroll
    for (int mt = 0; mt < 2; mt++)
#pragma unroll
        for (int nt = 0; nt < 7; nt++) acc[mt][nt] = f32x4{0.f, 0.f, 0.f, 0.f};

    const char* bbase = (const char*)Bp + (lq * 112 + c16) * 16;

    int wf0 = w0 + c16;       // mt=0 pixel w
    int wf1 = wf0 + 16;       // mt=1 pixel w

#pragma unroll
    for (int tap = 0; tap < 9; tap++) {
        int dy = tap / 3 - 1, dx = tap % 3 - 1;
        int hh = h + dy;
        bool vy = (unsigned)hh < 64u;
        int ww0 = wf0 + dx, ww1 = wf1 + dx;
        const char* ap0 = (vy && (unsigned)ww0 < 64u) ? cbase + (hh * 64 + ww0) * 128 : zpb;
        const char* ap1 = (vy && (unsigned)ww1 < 64u) ? cbase + (hh * 64 + ww1) * 128 : zpb;
#pragma unroll
        for (int half = 0; half < 2; half++) {
            int s = tap * 2 + half;
            bf16x8 a0 = *(const bf16x8*)(ap0 + koff + half * 64);
            bf16x8 a1 = *(const bf16x8*)(ap1 + koff + half * 64);
            const char* bptr = bbase + s * 7168;
            bf16x8 bf[7];
#pragma unroll
            for (int nt = 0; nt < 7; nt++) bf[nt] = *(const bf16x8*)(bptr + nt * 256);
#pragma unroll
            for (int nt = 0; nt < 7; nt++) {
                acc[0][nt] = __builtin_amdgcn_mfma_f32_16x16x32_bf16(a0, bf[nt], acc[0][nt], 0, 0, 0);
                acc[1][nt] = __builtin_amdgcn_mfma_f32_16x16x32_bf16(a1, bf[nt], acc[1][nt], 0, 0, 0);
            }
        }
    }

    // bias + fused softmax.  n = nt*16+c16 = 4j+sp; group (pixel,sp) = lanes c16^{4,8,12}.
    float bias[7];
#pragma unroll
    for (int nt = 0; nt < 7; nt++) {
        int n = nt * 16 + c16;
        bias[nt] = (n < 100) ? b_enc[n] : 0.f;
    }
    int nvalid = (c16 < 4) ? 7 : 6;

    float* mbase = maskT + ((size_t)nimg * 64 + h) * 6400;

#pragma unroll
    for (int mt = 0; mt < 2; mt++) {
#pragma unroll
        for (int r = 0; r < 4; r++) {
            float v[7];
#pragma unroll
            for (int nt = 0; nt < 7; nt++) v[nt] = acc[mt][nt][r] + bias[nt];
            float m = v[0];
#pragma unroll
            for (int nt = 1; nt < 7; nt++) if (nt < nvalid) m = fmaxf(m, v[nt]);
            m = fmaxf(m, __shfl_xor(m, 4));
            m = fmaxf(m, __shfl_xor(m, 8));
            float e[7];
            float s = 0.f;
#pragma unroll
            for (int nt = 0; nt < 7; nt++) {
                e[nt] = (nt < nvalid) ? __expf(v[nt] - m) : 0.f;
                s += e[nt];
            }
            s += __shfl_xor(s, 4);
            s += __shfl_xor(s, 8);
            float inv = 1.f / s;
            int wpix = w0 + mt * 16 + lq * 4 + r;     // pixel's w
            float* mp = mbase + wpix;
#pragma unroll
            for (int nt = 0; nt < 7; nt++)
                if (nt < nvalid) mp[(nt * 16 + c16) * 64] = e[nt] * inv;
        }
    }
}

// ---------------- kernel 3: reassembly (sp-split row-shuffle) ----------------
// Each block handles one subpixel-row pair sp in {2*spq, 2*spq+1} -> msk[50] regs.
// lane = w; dx taps via ds_bpermute; boundary folded into msk; channels 2-at-a-time
// with next-pair prefetch. grid 8192 = (n, h, cgb(8), spq(2)), XCD-swizzled so each
// XCD owns one image.
__global__ __launch_bounds__(256) void reassemble(const float* __restrict__ x,
                                                  const float* __restrict__ maskT,
                                                  float* __restrict__ out) {
    int lane = threadIdx.x & 63;       // = w
    int cq   = threadIdx.x >> 6;       // 0..3, wave-uniform
    int b    = blockIdx.x;
    int bs   = (b & 7) * 1024 + (b >> 3);   // bijective: 8192 = 8*1024
    int spq  = bs & 1;                 // r1
    int cgb  = (bs >> 1) & 7;
    int h    = (bs >> 4) & 63;
    int n    = bs >> 10;
    int c0   = cgb * 32 + cq * 8;

    const float* mrow = maskT + ((size_t)n * 64 + h) * 6400 + lane;

    int   yy[5];
    float vmy[5], vmx[5];
#pragma unroll
    for (int d = 0; d < 5; d++) {
        int y  = h + d - 2;
        int xc = lane + d - 2;
        yy[d]  = min(max(y, 0), 63) * 64;
        vmy[d] = ((unsigned)y  < 64u) ? 1.f : 0.f;
        vmx[d] = ((unsigned)xc < 64u) ? 1.f : 0.f;
    }

    // msk[2t+u] = mask weight for tap t, sp = 2*spq+u, boundary-folded
    float msk[50];
#pragma unroll
    for (int t = 0; t < 25; t++) {
        float f = vmy[t / 5] * vmx[t % 5];
        msk[2 * t + 0] = mrow[(4 * t + 2 * spq + 0) * 64] * f;
        msk[2 * t + 1] = mrow[(4 * t + 2 * spq + 1) * 64] * f;
    }

    int idxm2 = ((lane - 2) & 63) << 2;
    int idxm1 = ((lane - 1) & 63) << 2;
    int idxp1 = ((lane + 1) & 63) << 2;
    int idxp2 = ((lane + 2) & 63) << 2;

    const float* xbase = x + ((size_t)(n * CI + c0)) * 4096 + lane;
    float*       obase = out + ((size_t)(n * CI + c0) * 128 + 2 * h + spq) * 128 + 2 * lane;

    // channel pair 0 rows
    float ra[5], rb[5];
#pragma unroll
    for (int d = 0; d < 5; d++) {
        ra[d] = xbase[yy[d]];
        rb[d] = xbase[4096 + yy[d]];
    }

    for (int p = 0; p < 4; p++) {
        // prefetch next channel pair
        const float* xn = xbase + (size_t)((p < 3) ? (2 * p + 2) : 0) * 4096;
        float na[5], nb[5];
#pragma unroll
        for (int d = 0; d < 5; d++) {
            na[d] = xn[yy[d]];
            nb[d] = xn[4096 + yy[d]];
        }

        float a0 = 0.f, a1 = 0.f, b0 = 0.f, b1 = 0.f;
#pragma unroll
        for (int d = 0; d < 5; d++) {
            int   via = __float_as_int(ra[d]);
            int   vib = __float_as_int(rb[d]);
            float am2 = __int_as_float(__builtin_amdgcn_ds_bpermute(idxm2, via));
            float am1 = __int_as_float(__builtin_amdgcn_ds_bpermute(idxm1, via));
            float ap1 = __int_as_float(__builtin_amdgcn_ds_bpermute(idxp1, via));
            float ap2 = __int_as_float(__builtin_amdgcn_ds_bpermute(idxp2, via));
            float bm2 = __int_as_float(__builtin_amdgcn_ds_bpermute(idxm2, vib));
            float bm1 = __int_as_float(__builtin_amdgcn_ds_bpermute(idxm1, vib));
            float bp1 = __int_as_float(__builtin_amdgcn_ds_bpermute(idxp1, vib));
            float bp2 = __int_as_float(__builtin_amdgcn_ds_bpermute(idxp2, vib));
            const float* mk = msk + d * 10;
            a0 += mk[0] * am2; a1 += mk[1] * am2;
            b0 += mk[0] * bm2; b1 += mk[1] * bm2;
            a0 += mk[2] * am1; a1 += mk[3] * am1;
            b0 += mk[2] * bm1; b1 += mk[3] * bm1;
            a0 += mk[4] * ra[d]; a1 += mk[5] * ra[d];
            b0 += mk[4] * rb[d]; b1 += mk[5] * rb[d];
            a0 += mk[6] * ap1; a1 += mk[7] * ap1;
            b0 += mk[6] * bp1; b1 += mk[7] * bp1;
            a0 += mk[8] * ap2; a1 += mk[9] * ap2;
            b0 += mk[8] * bp2; b1 += mk[9] * bp2;
        }
        float* opa = obase + (size_t)(2 * p) * 16384;
        float* opb = obase + (size_t)(2 * p + 1) * 16384;
        reinterpret_cast<float2*>(opa)[0] = make_float2(a0, a1);
        reinterpret_cast<float2*>(opb)[0] = make_float2(b0, b1);

#pragma unroll
        for (int d = 0; d < 5; d++) { ra[d] = na[d]; rb[d] = nb[d]; }
    }
}

extern "C" void kernel_launch(void* const* d_in, const int* in_sizes, int n_in,
                              void* d_out, int out_size, void* d_ws, size_t ws_size,
                              hipStream_t stream) {
    const float* x      = (const float*)d_in[0];
    const float* w_comp = (const float*)d_in[1];
    const float* b_comp = (const float*)d_in[2];
    const float* w_enc  = (const float*)d_in[3];
    const float* b_enc  = (const float*)d_in[4];
    float* out = (float*)d_out;

    // workspace layout (bytes)
    char* ws = (char*)d_ws;
    float*          zp    = (float*)(ws + 0);                 // 256 B zeros
    float*          wT1   = (float*)(ws + 256);               // 64 KB
    unsigned short* Bp    = (unsigned short*)(ws + 65792);    // 129024 B
    unsigned short* comp  = (unsigned short*)(ws + 194816);   // 4 MB
    float*          maskT = (float*)(ws + 4389120);           // 13.1 MB
    // total ~17.5 MB

    prep_weights<<<252, 256, 0, stream>>>(w_comp, w_enc, wT1, Bp, zp);
    conv1x1<<<1024, 256, 0, stream>>>(x, wT1, b_comp, comp);
    conv3x3_mfma<<<1024, 64, 0, stream>>>(comp, Bp, b_enc, zp, maskT);
    reassemble<<<8192, 256, 0, stream>>>(x, maskT, out);
}

// Round 7
// 105.330 us; speedup vs baseline: 2.3778x; 1.2127x over previous
//
#include <hip/hip_runtime.h>

// CARAFE: x(8,256,64,64) fp32
//   -> conv1x1 (256->64) as swapped-operand bf16 MFMA (A=weights, B=x in-place) -> comp bf16 NHWC
//   -> conv3x3 (64->100) as bf16 MFMA GEMM (16 px/wave, N=112pad, K=576) + fused softmax
//   -> reassembly (row-shuffle, sp-split, XCD-swizzled) -> out(8,256,128,128) fp32
// K=5, G=1, S=2.
// mask layout: maskT[nimg][h][n=4j+sp][w].

#define CI 256

typedef __attribute__((ext_vector_type(8))) short bf16x8;
typedef __attribute__((ext_vector_type(4))) float f32x4;

__device__ inline unsigned short f2bf(float f) {
    unsigned u = __float_as_uint(f);
    unsigned r = (u + 0x7FFF + ((u >> 16) & 1)) >> 16;
    return (unsigned short)r;
}

// ---------------- kernel 0: weight prep ----------------
// wA[och][c] bf16 (64x256)   = w_comp (row-major, just bf16-cast)
// Bp[g][n][j] bf16           : k=g*8+j, tap=k>>6, c=k&63, n<100 -> w_enc[n*576+c*9+tap]
// zp: zero page for boundary taps
__global__ __launch_bounds__(256) void prep_weights(const float* __restrict__ w_comp,
                                                    const float* __restrict__ w_enc,
                                                    unsigned short* __restrict__ wA,
                                                    unsigned short* __restrict__ Bp,
                                                    float* __restrict__ zp) {
    int i = blockIdx.x * 256 + threadIdx.x;
    if (i < 64) zp[i] = 0.f;
    if (i < 64 * 256) wA[i] = f2bf(w_comp[i]);
    if (i < 72 * 112 * 8) {
        int j = i & 7;
        int n = (i >> 3) % 112;
        int g = i / (112 * 8);
        int k = g * 8 + j;
        int tap = k >> 6;
        int c = k & 63;
        float v = (n < 100) ? w_enc[n * 576 + c * 9 + tap] : 0.f;
        Bp[i] = f2bf(v);
    }
}

// ---------------- kernel 1: 1x1 conv via MFMA, swapped operands ----------------
// D[och][pixel] = W[och][c] * X[c][pixel].  A = wA (bf16, row-major), B = x (fp32,
// [c][pixel] natural layout -> per-lane 8 stride-4096 loads + cvt).
// 1 wave/block, 16 pixels/wave, all 64 och (4 M-tiles). grid 2048, XCD-swizzled.
__global__ __launch_bounds__(64) void conv1x1_mfma(const float* __restrict__ x,
                                                   const unsigned short* __restrict__ wA,
                                                   const float* __restrict__ b_comp,
                                                   unsigned short* __restrict__ comp) {
    int l   = threadIdx.x;
    int c16 = l & 15;
    int lq  = l >> 4;
    int b   = blockIdx.x;
    int bs  = (b & 7) * 256 + (b >> 3);   // bijective: 2048 = 8*256
    int P0  = bs * 16;
    int nimg = P0 >> 12;
    int hw   = P0 & 4095;

    const float* xp = x + (size_t)nimg * CI * 4096 + hw + c16;

    f32x4 acc[4];
#pragma unroll
    for (int mt = 0; mt < 4; mt++) acc[mt] = f32x4{0.f, 0.f, 0.f, 0.f};

#pragma unroll
    for (int ks = 0; ks < 8; ks++) {
        int k0 = ks * 32 + lq * 8;
        float v[8];
#pragma unroll
        for (int j = 0; j < 8; j++) v[j] = xp[(size_t)(k0 + j) * 4096];
        bf16x8 xb;
#pragma unroll
        for (int j = 0; j < 8; j++) xb[j] = (short)f2bf(v[j]);
#pragma unroll
        for (int mt = 0; mt < 4; mt++) {
            bf16x8 wf = *(const bf16x8*)(wA + (mt * 16 + c16) * 256 + k0);
            acc[mt] = __builtin_amdgcn_mfma_f32_16x16x32_bf16(wf, xb, acc[mt], 0, 0, 0);
        }
    }

    // D: col(c16)=pixel, row = 16mt + lq*4 + r = och
    unsigned short* cp = comp + (size_t)(P0 + c16) * 64;
#pragma unroll
    for (int mt = 0; mt < 4; mt++) {
        int och0 = mt * 16 + lq * 4;
        float4 bb = *reinterpret_cast<const float4*>(b_comp + och0);
        unsigned u0 = f2bf(acc[mt][0] + bb.x) | (f2bf(acc[mt][1] + bb.y) << 16);
        unsigned u1 = f2bf(acc[mt][2] + bb.z) | (f2bf(acc[mt][3] + bb.w) << 16);
        reinterpret_cast<uint2*>(cp + och0)[0] = uint2{u0, u1};
    }
}

// ---------------- kernel 2: 3x3 conv as bf16 MFMA GEMM + fused softmax ----------------
// 1 wave/block, 16 pixels/wave x 112 outputs (7 N-tiles), K=576 in 18 steps.
// grid 2048 (2 waves/SIMD), XCD-swizzled. Stores maskT[nimg][h][n][w].
__global__ __launch_bounds__(64) void conv3x3_mfma(const unsigned short* __restrict__ comp,
                                                   const unsigned short* __restrict__ Bp,
                                                   const float* __restrict__ b_enc,
                                                   const float* __restrict__ zp,
                                                   float* __restrict__ maskT) {
    int l   = threadIdx.x;
    int c16 = l & 15;
    int lq  = l >> 4;
    int b   = blockIdx.x;
    int bs  = (b & 7) * 256 + (b >> 3);   // bijective: 2048 = 8*256
    int P0  = bs * 16;
    int nimg = P0 >> 12;
    int h    = (P0 & 4095) >> 6;
    int w0   = P0 & 63;          // 0,16,32,48

    const char* cbase = (const char*)(comp + (size_t)nimg * 4096 * 64);
    const char* zpb   = (const char*)zp;
    int koff = lq * 16;          // (lq*8 bf16)*2B

    f32x4 acc[7];
#pragma unroll
    for (int nt = 0; nt < 7; nt++) acc[nt] = f32x4{0.f, 0.f, 0.f, 0.f};

    const char* bbase = (const char*)Bp + (lq * 112 + c16) * 16;
    int wf0 = w0 + c16;

#pragma unroll
    for (int tap = 0; tap < 9; tap++) {
        int dy = tap / 3 - 1, dx = tap % 3 - 1;
        int hh = h + dy;
        bool vy = (unsigned)hh < 64u;
        int ww0 = wf0 + dx;
        const char* ap0 = (vy && (unsigned)ww0 < 64u) ? cbase + (hh * 64 + ww0) * 128 : zpb;
#pragma unroll
        for (int half = 0; half < 2; half++) {
            int s = tap * 2 + half;
            bf16x8 a0 = *(const bf16x8*)(ap0 + koff + half * 64);
            const char* bptr = bbase + s * 7168;
            bf16x8 bf[7];
#pragma unroll
            for (int nt = 0; nt < 7; nt++) bf[nt] = *(const bf16x8*)(bptr + nt * 256);
#pragma unroll
            for (int nt = 0; nt < 7; nt++)
                acc[nt] = __builtin_amdgcn_mfma_f32_16x16x32_bf16(a0, bf[nt], acc[nt], 0, 0, 0);
        }
    }

    // bias + fused softmax.  n = nt*16+c16 = 4j+sp; group (pixel,sp) = lanes c16^{4,8,12}.
    float bias[7];
#pragma unroll
    for (int nt = 0; nt < 7; nt++) {
        int n = nt * 16 + c16;
        bias[nt] = (n < 100) ? b_enc[n] : 0.f;
    }
    int nvalid = (c16 < 4) ? 7 : 6;

    float* mbase = maskT + ((size_t)nimg * 64 + h) * 6400;

#pragma unroll
    for (int r = 0; r < 4; r++) {
        float v[7];
#pragma unroll
        for (int nt = 0; nt < 7; nt++) v[nt] = acc[nt][r] + bias[nt];
        float m = v[0];
#pragma unroll
        for (int nt = 1; nt < 7; nt++) if (nt < nvalid) m = fmaxf(m, v[nt]);
        m = fmaxf(m, __shfl_xor(m, 4));
        m = fmaxf(m, __shfl_xor(m, 8));
        float e[7];
        float s = 0.f;
#pragma unroll
        for (int nt = 0; nt < 7; nt++) {
            e[nt] = (nt < nvalid) ? __expf(v[nt] - m) : 0.f;
            s += e[nt];
        }
        s += __shfl_xor(s, 4);
        s += __shfl_xor(s, 8);
        float inv = 1.f / s;
        int wpix = w0 + lq * 4 + r;
        float* mp = mbase + wpix;
#pragma unroll
        for (int nt = 0; nt < 7; nt++)
            if (nt < nvalid) mp[(nt * 16 + c16) * 64] = e[nt] * inv;
    }
}

// ---------------- kernel 3: reassembly (sp-split row-shuffle) ----------------
__global__ __launch_bounds__(256) void reassemble(const float* __restrict__ x,
                                                  const float* __restrict__ maskT,
                                                  float* __restrict__ out) {
    int lane = threadIdx.x & 63;       // = w
    int cq   = threadIdx.x >> 6;       // 0..3, wave-uniform
    int b    = blockIdx.x;
    int bs   = (b & 7) * 1024 + (b >> 3);   // bijective: 8192 = 8*1024
    int spq  = bs & 1;                 // r1
    int cgb  = (bs >> 1) & 7;
    int h    = (bs >> 4) & 63;
    int n    = bs >> 10;
    int c0   = cgb * 32 + cq * 8;

    const float* mrow = maskT + ((size_t)n * 64 + h) * 6400 + lane;

    int   yy[5];
    float vmy[5], vmx[5];
#pragma unroll
    for (int d = 0; d < 5; d++) {
        int y  = h + d - 2;
        int xc = lane + d - 2;
        yy[d]  = min(max(y, 0), 63) * 64;
        vmy[d] = ((unsigned)y  < 64u) ? 1.f : 0.f;
        vmx[d] = ((unsigned)xc < 64u) ? 1.f : 0.f;
    }

    float msk[50];
#pragma unroll
    for (int t = 0; t < 25; t++) {
        float f = vmy[t / 5] * vmx[t % 5];
        msk[2 * t + 0] = mrow[(4 * t + 2 * spq + 0) * 64] * f;
        msk[2 * t + 1] = mrow[(4 * t + 2 * spq + 1) * 64] * f;
    }

    int idxm2 = ((lane - 2) & 63) << 2;
    int idxm1 = ((lane - 1) & 63) << 2;
    int idxp1 = ((lane + 1) & 63) << 2;
    int idxp2 = ((lane + 2) & 63) << 2;

    const float* xbase = x + ((size_t)(n * CI + c0)) * 4096 + lane;
    float*       obase = out + ((size_t)(n * CI + c0) * 128 + 2 * h + spq) * 128 + 2 * lane;

    float ra[5], rb[5];
#pragma unroll
    for (int d = 0; d < 5; d++) {
        ra[d] = xbase[yy[d]];
        rb[d] = xbase[4096 + yy[d]];
    }

    for (int p = 0; p < 4; p++) {
        const float* xn = xbase + (size_t)((p < 3) ? (2 * p + 2) : 0) * 4096;
        float na[5], nb[5];
#pragma unroll
        for (int d = 0; d < 5; d++) {
            na[d] = xn[yy[d]];
            nb[d] = xn[4096 + yy[d]];
        }

        float a0 = 0.f, a1 = 0.f, b0 = 0.f, b1 = 0.f;
#pragma unroll
        for (int d = 0; d < 5; d++) {
            int   via = __float_as_int(ra[d]);
            int   vib = __float_as_int(rb[d]);
            float am2 = __int_as_float(__builtin_amdgcn_ds_bpermute(idxm2, via));
            float am1 = __int_as_float(__builtin_amdgcn_ds_bpermute(idxm1, via));
            float ap1 = __int_as_float(__builtin_amdgcn_ds_bpermute(idxp1, via));
            float ap2 = __int_as_float(__builtin_amdgcn_ds_bpermute(idxp2, via));
            float bm2 = __int_as_float(__builtin_amdgcn_ds_bpermute(idxm2, vib));
            float bm1 = __int_as_float(__builtin_amdgcn_ds_bpermute(idxm1, vib));
            float bp1 = __int_as_float(__builtin_amdgcn_ds_bpermute(idxp1, vib));
            float bp2 = __int_as_float(__builtin_amdgcn_ds_bpermute(idxp2, vib));
            const float* mk = msk + d * 10;
            a0 += mk[0] * am2; a1 += mk[1] * am2;
            b0 += mk[0] * bm2; b1 += mk[1] * bm2;
            a0 += mk[2] * am1; a1 += mk[3] * am1;
            b0 += mk[2] * bm1; b1 += mk[3] * bm1;
            a0 += mk[4] * ra[d]; a1 += mk[5] * ra[d];
            b0 += mk[4] * rb[d]; b1 += mk[5] * rb[d];
            a0 += mk[6] * ap1; a1 += mk[7] * ap1;
            b0 += mk[6] * bp1; b1 += mk[7] * bp1;
            a0 += mk[8] * ap2; a1 += mk[9] * ap2;
            b0 += mk[8] * bp2; b1 += mk[9] * bp2;
        }
        float* opa = obase + (size_t)(2 * p) * 16384;
        float* opb = obase + (size_t)(2 * p + 1) * 16384;
        reinterpret_cast<float2*>(opa)[0] = make_float2(a0, a1);
        reinterpret_cast<float2*>(opb)[0] = make_float2(b0, b1);

#pragma unroll
        for (int d = 0; d < 5; d++) { ra[d] = na[d]; rb[d] = nb[d]; }
    }
}

extern "C" void kernel_launch(void* const* d_in, const int* in_sizes, int n_in,
                              void* d_out, int out_size, void* d_ws, size_t ws_size,
                              hipStream_t stream) {
    const float* x      = (const float*)d_in[0];
    const float* w_comp = (const float*)d_in[1];
    const float* b_comp = (const float*)d_in[2];
    const float* w_enc  = (const float*)d_in[3];
    const float* b_enc  = (const float*)d_in[4];
    float* out = (float*)d_out;

    // workspace layout (bytes)
    char* ws = (char*)d_ws;
    float*          zp    = (float*)(ws + 0);                 // 256 B zeros
    unsigned short* wA    = (unsigned short*)(ws + 256);      // 64*256*2 = 32768 B
    unsigned short* Bp    = (unsigned short*)(ws + 33024);    // 129024 B
    unsigned short* comp  = (unsigned short*)(ws + 162048);   // 4 MB
    float*          maskT = (float*)(ws + 4356352);           // 13.1 MB
    // total ~17.5 MB

    prep_weights<<<252, 256, 0, stream>>>(w_comp, w_enc, wA, Bp, zp);
    conv1x1_mfma<<<2048, 64, 0, stream>>>(x, wA, b_comp, comp);
    conv3x3_mfma<<<2048, 64, 0, stream>>>(comp, Bp, b_enc, zp, maskT);
    reassemble<<<8192, 256, 0, stream>>>(x, maskT, out);
}

// Round 8
// 89.932 us; speedup vs baseline: 2.7849x; 1.1712x over previous
//
#include <hip/hip_runtime.h>

// CARAFE: x(8,256,64,64) fp32
//   -> conv1x1 (256->64) as swapped-operand bf16 MFMA (A=weights, B=x in-place) -> comp bf16 NHWC
//   -> conv3x3 (64->100) as bf16 MFMA GEMM (16 px/wave, N=112pad, K=576) + fused softmax
//   -> reassembly (row-shuffle, sp-split, bf16-packed channel pairs) -> out fp32
// K=5, G=1, S=2.  mask layout: maskT[nimg][h][n=4j+sp][w].

#define CI 256

typedef __attribute__((ext_vector_type(8))) short bf16x8;
typedef __attribute__((ext_vector_type(4))) float f32x4;

__device__ inline unsigned short f2bf(float f) {
    unsigned u = __float_as_uint(f);
    unsigned r = (u + 0x7FFF + ((u >> 16) & 1)) >> 16;
    return (unsigned short)r;
}

__device__ inline unsigned cvt_pk_bf16(float lo, float hi) {
    unsigned r;
    asm("v_cvt_pk_bf16_f32 %0, %1, %2" : "=v"(r) : "v"(lo), "v"(hi));
    return r;
}

// ---------------- kernel 0: weight prep ----------------
__global__ __launch_bounds__(256) void prep_weights(const float* __restrict__ w_comp,
                                                    const float* __restrict__ w_enc,
                                                    unsigned short* __restrict__ wA,
                                                    unsigned short* __restrict__ Bp,
                                                    float* __restrict__ zp) {
    int i = blockIdx.x * 256 + threadIdx.x;
    if (i < 64) zp[i] = 0.f;
    if (i < 64 * 256) wA[i] = f2bf(w_comp[i]);
    if (i < 72 * 112 * 8) {
        int j = i & 7;
        int n = (i >> 3) % 112;
        int g = i / (112 * 8);
        int k = g * 8 + j;
        int tap = k >> 6;
        int c = k & 63;
        float v = (n < 100) ? w_enc[n * 576 + c * 9 + tap] : 0.f;
        Bp[i] = f2bf(v);
    }
}

// ---------------- kernel 1: 1x1 conv via MFMA, swapped operands ----------------
__global__ __launch_bounds__(64) void conv1x1_mfma(const float* __restrict__ x,
                                                   const unsigned short* __restrict__ wA,
                                                   const float* __restrict__ b_comp,
                                                   unsigned short* __restrict__ comp) {
    int l   = threadIdx.x;
    int c16 = l & 15;
    int lq  = l >> 4;
    int b   = blockIdx.x;
    int bs  = (b & 7) * 256 + (b >> 3);   // bijective: 2048 = 8*256
    int P0  = bs * 16;
    int nimg = P0 >> 12;
    int hw   = P0 & 4095;

    const float* xp = x + (size_t)nimg * CI * 4096 + hw + c16;

    f32x4 acc[4];
#pragma unroll
    for (int mt = 0; mt < 4; mt++) acc[mt] = f32x4{0.f, 0.f, 0.f, 0.f};

#pragma unroll
    for (int ks = 0; ks < 8; ks++) {
        int k0 = ks * 32 + lq * 8;
        float v[8];
#pragma unroll
        for (int j = 0; j < 8; j++) v[j] = xp[(size_t)(k0 + j) * 4096];
        bf16x8 xb;
#pragma unroll
        for (int j = 0; j < 8; j++) xb[j] = (short)f2bf(v[j]);
#pragma unroll
        for (int mt = 0; mt < 4; mt++) {
            bf16x8 wf = *(const bf16x8*)(wA + (mt * 16 + c16) * 256 + k0);
            acc[mt] = __builtin_amdgcn_mfma_f32_16x16x32_bf16(wf, xb, acc[mt], 0, 0, 0);
        }
    }

    unsigned short* cp = comp + (size_t)(P0 + c16) * 64;
#pragma unroll
    for (int mt = 0; mt < 4; mt++) {
        int och0 = mt * 16 + lq * 4;
        float4 bb = *reinterpret_cast<const float4*>(b_comp + och0);
        unsigned u0 = f2bf(acc[mt][0] + bb.x) | (f2bf(acc[mt][1] + bb.y) << 16);
        unsigned u1 = f2bf(acc[mt][2] + bb.z) | (f2bf(acc[mt][3] + bb.w) << 16);
        reinterpret_cast<uint2*>(cp + och0)[0] = uint2{u0, u1};
    }
}

// ---------------- kernel 2: 3x3 conv as bf16 MFMA GEMM + fused softmax ----------------
__global__ __launch_bounds__(64) void conv3x3_mfma(const unsigned short* __restrict__ comp,
                                                   const unsigned short* __restrict__ Bp,
                                                   const float* __restrict__ b_enc,
                                                   const float* __restrict__ zp,
                                                   float* __restrict__ maskT) {
    int l   = threadIdx.x;
    int c16 = l & 15;
    int lq  = l >> 4;
    int b   = blockIdx.x;
    int bs  = (b & 7) * 256 + (b >> 3);   // bijective: 2048 = 8*256
    int P0  = bs * 16;
    int nimg = P0 >> 12;
    int h    = (P0 & 4095) >> 6;
    int w0   = P0 & 63;          // 0,16,32,48

    const char* cbase = (const char*)(comp + (size_t)nimg * 4096 * 64);
    const char* zpb   = (const char*)zp;
    int koff = lq * 16;

    f32x4 acc[7];
#pragma unroll
    for (int nt = 0; nt < 7; nt++) acc[nt] = f32x4{0.f, 0.f, 0.f, 0.f};

    const char* bbase = (const char*)Bp + (lq * 112 + c16) * 16;
    int wf0 = w0 + c16;

#pragma unroll
    for (int tap = 0; tap < 9; tap++) {
        int dy = tap / 3 - 1, dx = tap % 3 - 1;
        int hh = h + dy;
        bool vy = (unsigned)hh < 64u;
        int ww0 = wf0 + dx;
        const char* ap0 = (vy && (unsigned)ww0 < 64u) ? cbase + (hh * 64 + ww0) * 128 : zpb;
#pragma unroll
        for (int half = 0; half < 2; half++) {
            int s = tap * 2 + half;
            bf16x8 a0 = *(const bf16x8*)(ap0 + koff + half * 64);
            const char* bptr = bbase + s * 7168;
            bf16x8 bf[7];
#pragma unroll
            for (int nt = 0; nt < 7; nt++) bf[nt] = *(const bf16x8*)(bptr + nt * 256);
#pragma unroll
            for (int nt = 0; nt < 7; nt++)
                acc[nt] = __builtin_amdgcn_mfma_f32_16x16x32_bf16(a0, bf[nt], acc[nt], 0, 0, 0);
        }
    }

    float bias[7];
#pragma unroll
    for (int nt = 0; nt < 7; nt++) {
        int n = nt * 16 + c16;
        bias[nt] = (n < 100) ? b_enc[n] : 0.f;
    }
    int nvalid = (c16 < 4) ? 7 : 6;

    float* mbase = maskT + ((size_t)nimg * 64 + h) * 6400;

#pragma unroll
    for (int r = 0; r < 4; r++) {
        float v[7];
#pragma unroll
        for (int nt = 0; nt < 7; nt++) v[nt] = acc[nt][r] + bias[nt];
        float m = v[0];
#pragma unroll
        for (int nt = 1; nt < 7; nt++) if (nt < nvalid) m = fmaxf(m, v[nt]);
        m = fmaxf(m, __shfl_xor(m, 4));
        m = fmaxf(m, __shfl_xor(m, 8));
        float e[7];
        float s = 0.f;
#pragma unroll
        for (int nt = 0; nt < 7; nt++) {
            e[nt] = (nt < nvalid) ? __expf(v[nt] - m) : 0.f;
            s += e[nt];
        }
        s += __shfl_xor(s, 4);
        s += __shfl_xor(s, 8);
        float inv = 1.f / s;
        int wpix = w0 + lq * 4 + r;
        float* mp = mbase + wpix;
#pragma unroll
        for (int nt = 0; nt < 7; nt++)
            if (nt < nvalid) mp[(nt * 16 + c16) * 64] = e[nt] * inv;
    }
}

// ---------------- kernel 3: reassembly (sp-split, bf16-packed channel pairs) ----------------
// lane = w. Channel pair's rows packed as 2xbf16 in one reg -> ONE bpermute per
// shift serves both channels (DS halved: 160 -> 80 per thread). Center tap uses
// the original f32 values. Boundary zeros folded into msk.
__global__ __launch_bounds__(256) void reassemble(const float* __restrict__ x,
                                                  const float* __restrict__ maskT,
                                                  float* __restrict__ out) {
    int lane = threadIdx.x & 63;       // = w
    int cq   = threadIdx.x >> 6;       // 0..3, wave-uniform
    int b    = blockIdx.x;
    int bs   = (b & 7) * 1024 + (b >> 3);   // bijective: 8192 = 8*1024
    int spq  = bs & 1;                 // r1
    int cgb  = (bs >> 1) & 7;
    int h    = (bs >> 4) & 63;
    int n    = bs >> 10;
    int c0   = cgb * 32 + cq * 8;

    const float* mrow = maskT + ((size_t)n * 64 + h) * 6400 + lane;

    int   yy[5];
    float vmy[5], vmx[5];
#pragma unroll
    for (int d = 0; d < 5; d++) {
        int y  = h + d - 2;
        int xc = lane + d - 2;
        yy[d]  = min(max(y, 0), 63) * 64;
        vmy[d] = ((unsigned)y  < 64u) ? 1.f : 0.f;
        vmx[d] = ((unsigned)xc < 64u) ? 1.f : 0.f;
    }

    float msk[50];
#pragma unroll
    for (int t = 0; t < 25; t++) {
        float f = vmy[t / 5] * vmx[t % 5];
        msk[2 * t + 0] = mrow[(4 * t + 2 * spq + 0) * 64] * f;
        msk[2 * t + 1] = mrow[(4 * t + 2 * spq + 1) * 64] * f;
    }

    int idxm2 = ((lane - 2) & 63) << 2;
    int idxm1 = ((lane - 1) & 63) << 2;
    int idxp1 = ((lane + 1) & 63) << 2;
    int idxp2 = ((lane + 2) & 63) << 2;

    const float* xbase = x + ((size_t)(n * CI + c0)) * 4096 + lane;
    float*       obase = out + ((size_t)(n * CI + c0) * 128 + 2 * h + spq) * 128 + 2 * lane;

    // channel pair 0 rows (f32 for center tap) + packed bf16 pair for shifts
    float ra[5], rb[5];
    unsigned pk[5];
#pragma unroll
    for (int d = 0; d < 5; d++) {
        ra[d] = xbase[yy[d]];
        rb[d] = xbase[4096 + yy[d]];
        pk[d] = cvt_pk_bf16(ra[d], rb[d]);
    }

    for (int p = 0; p < 4; p++) {
        const float* xn = xbase + (size_t)((p < 3) ? (2 * p + 2) : 0) * 4096;
        float na[5], nb[5];
#pragma unroll
        for (int d = 0; d < 5; d++) {
            na[d] = xn[yy[d]];
            nb[d] = xn[4096 + yy[d]];
        }

        float a0 = 0.f, a1 = 0.f, b0 = 0.f, b1 = 0.f;
#pragma unroll
        for (int d = 0; d < 5; d++) {
            int pv = (int)pk[d];
            int sm2 = __builtin_amdgcn_ds_bpermute(idxm2, pv);
            int sm1 = __builtin_amdgcn_ds_bpermute(idxm1, pv);
            int sp1 = __builtin_amdgcn_ds_bpermute(idxp1, pv);
            int sp2 = __builtin_amdgcn_ds_bpermute(idxp2, pv);
            float am2 = __int_as_float((unsigned)sm2 << 16);
            float bm2 = __int_as_float((unsigned)sm2 & 0xffff0000u);
            float am1 = __int_as_float((unsigned)sm1 << 16);
            float bm1 = __int_as_float((unsigned)sm1 & 0xffff0000u);
            float ap1 = __int_as_float((unsigned)sp1 << 16);
            float bp1 = __int_as_float((unsigned)sp1 & 0xffff0000u);
            float ap2 = __int_as_float((unsigned)sp2 << 16);
            float bp2 = __int_as_float((unsigned)sp2 & 0xffff0000u);
            const float* mk = msk + d * 10;
            a0 += mk[0] * am2; a1 += mk[1] * am2;
            b0 += mk[0] * bm2; b1 += mk[1] * bm2;
            a0 += mk[2] * am1; a1 += mk[3] * am1;
            b0 += mk[2] * bm1; b1 += mk[3] * bm1;
            a0 += mk[4] * ra[d]; a1 += mk[5] * ra[d];
            b0 += mk[4] * rb[d]; b1 += mk[5] * rb[d];
            a0 += mk[6] * ap1; a1 += mk[7] * ap1;
            b0 += mk[6] * bp1; b1 += mk[7] * bp1;
            a0 += mk[8] * ap2; a1 += mk[9] * ap2;
            b0 += mk[8] * bp2; b1 += mk[9] * bp2;
        }
        float* opa = obase + (size_t)(2 * p) * 16384;
        float* opb = obase + (size_t)(2 * p + 1) * 16384;
        reinterpret_cast<float2*>(opa)[0] = make_float2(a0, a1);
        reinterpret_cast<float2*>(opb)[0] = make_float2(b0, b1);

#pragma unroll
        for (int d = 0; d < 5; d++) {
            ra[d] = na[d];
            rb[d] = nb[d];
            pk[d] = cvt_pk_bf16(na[d], nb[d]);
        }
    }
}

extern "C" void kernel_launch(void* const* d_in, const int* in_sizes, int n_in,
                              void* d_out, int out_size, void* d_ws, size_t ws_size,
                              hipStream_t stream) {
    const float* x      = (const float*)d_in[0];
    const float* w_comp = (const float*)d_in[1];
    const float* b_comp = (const float*)d_in[2];
    const float* w_enc  = (const float*)d_in[3];
    const float* b_enc  = (const float*)d_in[4];
    float* out = (float*)d_out;

    // workspace layout (bytes)
    char* ws = (char*)d_ws;
    float*          zp    = (float*)(ws + 0);                 // 256 B zeros
    unsigned short* wA    = (unsigned short*)(ws + 256);      // 32768 B
    unsigned short* Bp    = (unsigned short*)(ws + 33024);    // 129024 B
    unsigned short* comp  = (unsigned short*)(ws + 162048);   // 4 MB
    float*          maskT = (float*)(ws + 4356352);           // 13.1 MB
    // total ~17.5 MB

    prep_weights<<<252, 256, 0, stream>>>(w_comp, w_enc, wA, Bp, zp);
    conv1x1_mfma<<<2048, 64, 0, stream>>>(x, wA, b_comp, comp);
    conv3x3_mfma<<<2048, 64, 0, stream>>>(comp, Bp, b_enc, zp, maskT);
    reassemble<<<8192, 256, 0, stream>>>(x, maskT, out);
}

// Round 9
// 85.594 us; speedup vs baseline: 2.9260x; 1.0507x over previous
//
#include <hip/hip_runtime.h>

// CARAFE: x(8,256,64,64) fp32
//   -> conv1x1 (256->64) as swapped-operand bf16 MFMA -> comp bf16 NHWC
//   -> conv3x3 (64->100) bf16 MFMA, B staged in LDS (dbuf, global_load_lds) + fused softmax
//   -> reassembly (row-shuffle, sp-split, bf16-packed channel pairs) -> out fp32
// K=5, G=1, S=2.  mask layout: maskT[nimg][h][n=4j+sp][w].

#define CI 256

typedef __attribute__((ext_vector_type(8))) short bf16x8;
typedef __attribute__((ext_vector_type(4))) float f32x4;

__device__ inline unsigned short f2bf(float f) {
    unsigned u = __float_as_uint(f);
    unsigned r = (u + 0x7FFF + ((u >> 16) & 1)) >> 16;
    return (unsigned short)r;
}

__device__ inline unsigned cvt_pk_bf16(float lo, float hi) {
    unsigned r;
    asm("v_cvt_pk_bf16_f32 %0, %1, %2" : "=v"(r) : "v"(lo), "v"(hi));
    return r;
}

// ---------------- kernel 0: weight prep ----------------
__global__ __launch_bounds__(256) void prep_weights(const float* __restrict__ w_comp,
                                                    const float* __restrict__ w_enc,
                                                    unsigned short* __restrict__ wA,
                                                    unsigned short* __restrict__ Bp,
                                                    float* __restrict__ zp) {
    int i = blockIdx.x * 256 + threadIdx.x;
    if (i < 64) zp[i] = 0.f;
    if (i < 64 * 256) wA[i] = f2bf(w_comp[i]);
    if (i < 72 * 112 * 8) {
        int j = i & 7;
        int n = (i >> 3) % 112;
        int g = i / (112 * 8);
        int k = g * 8 + j;
        int tap = k >> 6;
        int c = k & 63;
        float v = (n < 100) ? w_enc[n * 576 + c * 9 + tap] : 0.f;
        Bp[i] = f2bf(v);
    }
}

// ---------------- kernel 1: 1x1 conv via MFMA, swapped operands ----------------
__global__ __launch_bounds__(64) void conv1x1_mfma(const float* __restrict__ x,
                                                   const unsigned short* __restrict__ wA,
                                                   const float* __restrict__ b_comp,
                                                   unsigned short* __restrict__ comp) {
    int l   = threadIdx.x;
    int c16 = l & 15;
    int lq  = l >> 4;
    int b   = blockIdx.x;
    int bs  = (b & 7) * 256 + (b >> 3);   // bijective: 2048 = 8*256
    int P0  = bs * 16;
    int nimg = P0 >> 12;
    int hw   = P0 & 4095;

    const float* xp = x + (size_t)nimg * CI * 4096 + hw + c16;

    f32x4 acc[4];
#pragma unroll
    for (int mt = 0; mt < 4; mt++) acc[mt] = f32x4{0.f, 0.f, 0.f, 0.f};

#pragma unroll
    for (int ks = 0; ks < 8; ks++) {
        int k0 = ks * 32 + lq * 8;
        float v[8];
#pragma unroll
        for (int j = 0; j < 8; j++) v[j] = xp[(size_t)(k0 + j) * 4096];
        bf16x8 xb;
#pragma unroll
        for (int j = 0; j < 8; j++) xb[j] = (short)f2bf(v[j]);
#pragma unroll
        for (int mt = 0; mt < 4; mt++) {
            bf16x8 wf = *(const bf16x8*)(wA + (mt * 16 + c16) * 256 + k0);
            acc[mt] = __builtin_amdgcn_mfma_f32_16x16x32_bf16(wf, xb, acc[mt], 0, 0, 0);
        }
    }

    unsigned short* cp = comp + (size_t)(P0 + c16) * 64;
#pragma unroll
    for (int mt = 0; mt < 4; mt++) {
        int och0 = mt * 16 + lq * 4;
        float4 bb = *reinterpret_cast<const float4*>(b_comp + och0);
        unsigned u0 = f2bf(acc[mt][0] + bb.x) | (f2bf(acc[mt][1] + bb.y) << 16);
        unsigned u1 = f2bf(acc[mt][2] + bb.z) | (f2bf(acc[mt][3] + bb.w) << 16);
        reinterpret_cast<uint2*>(cp + och0)[0] = uint2{u0, u1};
    }
}

// ---------------- kernel 2: 3x3 conv, B staged in LDS (double-buffered) ----------------
// Block = 4 waves = one row (64 px); wave wv owns px [wv*16, wv*16+16).
// Per K-step s (18 total, 32k each): stage Bs[s+1] (7KB via global_load_lds x7),
// ds_read 7 B-frags from Bs[s], 1 global A-frag, 7 MFMA, barrier.
// grid 512, XCD-swizzled (each XCD owns one image).
__global__ __launch_bounds__(256) void conv3x3_mfma(const unsigned short* __restrict__ comp,
                                                    const unsigned short* __restrict__ Bp,
                                                    const float* __restrict__ b_enc,
                                                    const float* __restrict__ zp,
                                                    float* __restrict__ maskT) {
    __shared__ char Bs[2][7168];
    int tid = threadIdx.x;
    int wv  = tid >> 6;          // 0..3 (wave id)
    int l   = tid & 63;
    int c16 = l & 15;
    int lq  = l >> 4;
    int b   = blockIdx.x;
    int bs  = (b & 7) * 64 + (b >> 3);   // bijective: 512 = 8*64 -> XCD x owns image x
    int nimg = bs >> 6;
    int h    = bs & 63;
    int w0   = wv * 16;

    const char* cbase = (const char*)(comp + (size_t)nimg * 4096 * 64);
    const char* zpb   = (const char*)zp;

    // stage K-step s into buffer buf: 7 x 1024B, wave wv issues insts {wv, wv+4}
#define STAGE(s_, buf_)                                                                   \
    {                                                                                     \
        const char* src_ = (const char*)Bp + (s_)*7168 + l * 16;                          \
        for (int inst_ = wv; inst_ < 7; inst_ += 4) {                                     \
            __builtin_amdgcn_global_load_lds(                                             \
                (const __attribute__((address_space(1))) void*)(src_ + inst_ * 1024),     \
                (__attribute__((address_space(3))) void*)(&Bs[buf_][inst_ * 1024]),       \
                16, 0, 0);                                                                \
        }                                                                                 \
    }

    f32x4 acc[7];
#pragma unroll
    for (int nt = 0; nt < 7; nt++) acc[nt] = f32x4{0.f, 0.f, 0.f, 0.f};

    const int dyt[9] = {-1, -1, -1, 0, 0, 0, 1, 1, 1};
    const int dxt[9] = {-1, 0, 1, -1, 0, 1, -1, 0, 1};

    STAGE(0, 0);
    __syncthreads();   // drains vmcnt -> Bs[0] ready

#pragma unroll
    for (int s = 0; s < 18; s++) {
        int cur = s & 1;
        if (s < 17) STAGE(s + 1, cur ^ 1);

        int tap = s >> 1, half = s & 1;
        int hh = h + dyt[tap];
        int ww = w0 + c16 + dxt[tap];
        const char* ap = ((unsigned)hh < 64u && (unsigned)ww < 64u)
                             ? cbase + (hh * 64 + ww) * 128 : zpb;
        bf16x8 a = *(const bf16x8*)(ap + lq * 16 + half * 64);

        bf16x8 bf[7];
#pragma unroll
        for (int nt = 0; nt < 7; nt++)
            bf[nt] = *(const bf16x8*)(&Bs[cur][(lq * 112 + nt * 16 + c16) * 16]);
#pragma unroll
        for (int nt = 0; nt < 7; nt++)
            acc[nt] = __builtin_amdgcn_mfma_f32_16x16x32_bf16(a, bf[nt], acc[nt], 0, 0, 0);

        __syncthreads();   // stage(s+1) complete; all waves done reading Bs[cur]
    }
#undef STAGE

    // bias + fused softmax.  n = nt*16+c16 = 4j+sp; group (pixel,sp) = lanes c16^{4,8,12}.
    float bias[7];
#pragma unroll
    for (int nt = 0; nt < 7; nt++) {
        int n = nt * 16 + c16;
        bias[nt] = (n < 100) ? b_enc[n] : 0.f;
    }
    int nvalid = (c16 < 4) ? 7 : 6;

    float* mbase = maskT + ((size_t)nimg * 64 + h) * 6400;

#pragma unroll
    for (int r = 0; r < 4; r++) {
        float v[7];
#pragma unroll
        for (int nt = 0; nt < 7; nt++) v[nt] = acc[nt][r] + bias[nt];
        float m = v[0];
#pragma unroll
        for (int nt = 1; nt < 7; nt++) if (nt < nvalid) m = fmaxf(m, v[nt]);
        m = fmaxf(m, __shfl_xor(m, 4));
        m = fmaxf(m, __shfl_xor(m, 8));
        float e[7];
        float s = 0.f;
#pragma unroll
        for (int nt = 0; nt < 7; nt++) {
            e[nt] = (nt < nvalid) ? __expf(v[nt] - m) : 0.f;
            s += e[nt];
        }
        s += __shfl_xor(s, 4);
        s += __shfl_xor(s, 8);
        float inv = 1.f / s;
        int wpix = w0 + lq * 4 + r;
        float* mp = mbase + wpix;
#pragma unroll
        for (int nt = 0; nt < 7; nt++)
            if (nt < nvalid) mp[(nt * 16 + c16) * 64] = e[nt] * inv;
    }
}

// ---------------- kernel 3: reassembly (sp-split, bf16-packed channel pairs) ----------------
__global__ __launch_bounds__(256) void reassemble(const float* __restrict__ x,
                                                  const float* __restrict__ maskT,
                                                  float* __restrict__ out) {
    int lane = threadIdx.x & 63;       // = w
    int cq   = threadIdx.x >> 6;       // 0..3, wave-uniform
    int b    = blockIdx.x;
    int bs   = (b & 7) * 1024 + (b >> 3);   // bijective: 8192 = 8*1024
    int spq  = bs & 1;                 // r1
    int cgb  = (bs >> 1) & 7;
    int h    = (bs >> 4) & 63;
    int n    = bs >> 10;
    int c0   = cgb * 32 + cq * 8;

    const float* mrow = maskT + ((size_t)n * 64 + h) * 6400 + lane;

    int   yy[5];
    float vmy[5], vmx[5];
#pragma unroll
    for (int d = 0; d < 5; d++) {
        int y  = h + d - 2;
        int xc = lane + d - 2;
        yy[d]  = min(max(y, 0), 63) * 64;
        vmy[d] = ((unsigned)y  < 64u) ? 1.f : 0.f;
        vmx[d] = ((unsigned)xc < 64u) ? 1.f : 0.f;
    }

    float msk[50];
#pragma unroll
    for (int t = 0; t < 25; t++) {
        float f = vmy[t / 5] * vmx[t % 5];
        msk[2 * t + 0] = mrow[(4 * t + 2 * spq + 0) * 64] * f;
        msk[2 * t + 1] = mrow[(4 * t + 2 * spq + 1) * 64] * f;
    }

    int idxm2 = ((lane - 2) & 63) << 2;
    int idxm1 = ((lane - 1) & 63) << 2;
    int idxp1 = ((lane + 1) & 63) << 2;
    int idxp2 = ((lane + 2) & 63) << 2;

    const float* xbase = x + ((size_t)(n * CI + c0)) * 4096 + lane;
    float*       obase = out + ((size_t)(n * CI + c0) * 128 + 2 * h + spq) * 128 + 2 * lane;

    float ra[5], rb[5];
    unsigned pk[5];
#pragma unroll
    for (int d = 0; d < 5; d++) {
        ra[d] = xbase[yy[d]];
        rb[d] = xbase[4096 + yy[d]];
        pk[d] = cvt_pk_bf16(ra[d], rb[d]);
    }

    for (int p = 0; p < 4; p++) {
        const float* xn = xbase + (size_t)((p < 3) ? (2 * p + 2) : 0) * 4096;
        float na[5], nb[5];
#pragma unroll
        for (int d = 0; d < 5; d++) {
            na[d] = xn[yy[d]];
            nb[d] = xn[4096 + yy[d]];
        }

        float a0 = 0.f, a1 = 0.f, b0 = 0.f, b1 = 0.f;
#pragma unroll
        for (int d = 0; d < 5; d++) {
            int pv = (int)pk[d];
            int sm2 = __builtin_amdgcn_ds_bpermute(idxm2, pv);
            int sm1 = __builtin_amdgcn_ds_bpermute(idxm1, pv);
            int sp1 = __builtin_amdgcn_ds_bpermute(idxp1, pv);
            int sp2 = __builtin_amdgcn_ds_bpermute(idxp2, pv);
            float am2 = __int_as_float((unsigned)sm2 << 16);
            float bm2 = __int_as_float((unsigned)sm2 & 0xffff0000u);
            float am1 = __int_as_float((unsigned)sm1 << 16);
            float bm1 = __int_as_float((unsigned)sm1 & 0xffff0000u);
            float ap1 = __int_as_float((unsigned)sp1 << 16);
            float bp1 = __int_as_float((unsigned)sp1 & 0xffff0000u);
            float ap2 = __int_as_float((unsigned)sp2 << 16);
            float bp2 = __int_as_float((unsigned)sp2 & 0xffff0000u);
            const float* mk = msk + d * 10;
            a0 += mk[0] * am2; a1 += mk[1] * am2;
            b0 += mk[0] * bm2; b1 += mk[1] * bm2;
            a0 += mk[2] * am1; a1 += mk[3] * am1;
            b0 += mk[2] * bm1; b1 += mk[3] * bm1;
            a0 += mk[4] * ra[d]; a1 += mk[5] * ra[d];
            b0 += mk[4] * rb[d]; b1 += mk[5] * rb[d];
            a0 += mk[6] * ap1; a1 += mk[7] * ap1;
            b0 += mk[6] * bp1; b1 += mk[7] * bp1;
            a0 += mk[8] * ap2; a1 += mk[9] * ap2;
            b0 += mk[8] * bp2; b1 += mk[9] * bp2;
        }
        float* opa = obase + (size_t)(2 * p) * 16384;
        float* opb = obase + (size_t)(2 * p + 1) * 16384;
        reinterpret_cast<float2*>(opa)[0] = make_float2(a0, a1);
        reinterpret_cast<float2*>(opb)[0] = make_float2(b0, b1);

#pragma unroll
        for (int d = 0; d < 5; d++) {
            ra[d] = na[d];
            rb[d] = nb[d];
            pk[d] = cvt_pk_bf16(na[d], nb[d]);
        }
    }
}

extern "C" void kernel_launch(void* const* d_in, const int* in_sizes, int n_in,
                              void* d_out, int out_size, void* d_ws, size_t ws_size,
                              hipStream_t stream) {
    const float* x      = (const float*)d_in[0];
    const float* w_comp = (const float*)d_in[1];
    const float* b_comp = (const float*)d_in[2];
    const float* w_enc  = (const float*)d_in[3];
    const float* b_enc  = (const float*)d_in[4];
    float* out = (float*)d_out;

    // workspace layout (bytes)
    char* ws = (char*)d_ws;
    float*          zp    = (float*)(ws + 0);                 // 256 B zeros
    unsigned short* wA    = (unsigned short*)(ws + 256);      // 32768 B
    unsigned short* Bp    = (unsigned short*)(ws + 33024);    // 129024 B
    unsigned short* comp  = (unsigned short*)(ws + 162048);   // 4 MB
    float*          maskT = (float*)(ws + 4356352);           // 13.1 MB
    // total ~17.5 MB

    prep_weights<<<252, 256, 0, stream>>>(w_comp, w_enc, wA, Bp, zp);
    conv1x1_mfma<<<2048, 64, 0, stream>>>(x, wA, b_comp, comp);
    conv3x3_mfma<<<512, 256, 0, stream>>>(comp, Bp, b_enc, zp, maskT);
    reassemble<<<8192, 256, 0, stream>>>(x, maskT, out);
}

// Round 10
// 76.963 us; speedup vs baseline: 3.2542x; 1.1122x over previous
//
#include <hip/hip_runtime.h>

// CARAFE: x(8,256,64,64) fp32
//   -> conv1x1 (256->64) as swapped-operand bf16 MFMA -> comp bf16 NHWC
//   -> conv3x3 (64->100) bf16 MFMA, B staged in LDS + fused softmax, mask packed bf16-pairs
//   -> reassembly (merged subpixel rows, packed bpermute) -> out fp32
// K=5, G=1, S=2.
// maskP layout: [nimg][h][n2(50)][w] uint, n2=2t+spq, pair=(sp=2spq, sp=2spq+1) bf16 (lo,hi).

#define CI 256

typedef __attribute__((ext_vector_type(8))) short bf16x8;
typedef __attribute__((ext_vector_type(4))) float f32x4;

__device__ inline unsigned short f2bf(float f) {
    unsigned u = __float_as_uint(f);
    unsigned r = (u + 0x7FFF + ((u >> 16) & 1)) >> 16;
    return (unsigned short)r;
}

__device__ inline unsigned cvt_pk_bf16(float lo, float hi) {
    unsigned r;
    asm("v_cvt_pk_bf16_f32 %0, %1, %2" : "=v"(r) : "v"(lo), "v"(hi));
    return r;
}

__device__ inline float bf_lo(unsigned u) { return __int_as_float(u << 16); }
__device__ inline float bf_hi(unsigned u) { return __int_as_float(u & 0xffff0000u); }

// ---------------- kernel 0: weight prep ----------------
__global__ __launch_bounds__(256) void prep_weights(const float* __restrict__ w_comp,
                                                    const float* __restrict__ w_enc,
                                                    unsigned short* __restrict__ wA,
                                                    unsigned short* __restrict__ Bp,
                                                    float* __restrict__ zp) {
    int i = blockIdx.x * 256 + threadIdx.x;
    if (i < 64) zp[i] = 0.f;
    if (i < 64 * 256) wA[i] = f2bf(w_comp[i]);
    if (i < 72 * 112 * 8) {
        int j = i & 7;
        int n = (i >> 3) % 112;
        int g = i / (112 * 8);
        int k = g * 8 + j;
        int tap = k >> 6;
        int c = k & 63;
        float v = (n < 100) ? w_enc[n * 576 + c * 9 + tap] : 0.f;
        Bp[i] = f2bf(v);
    }
}

// ---------------- kernel 1: 1x1 conv via MFMA, swapped operands ----------------
__global__ __launch_bounds__(64) void conv1x1_mfma(const float* __restrict__ x,
                                                   const unsigned short* __restrict__ wA,
                                                   const float* __restrict__ b_comp,
                                                   unsigned short* __restrict__ comp) {
    int l   = threadIdx.x;
    int c16 = l & 15;
    int lq  = l >> 4;
    int b   = blockIdx.x;
    int bs  = (b & 7) * 256 + (b >> 3);   // bijective: 2048 = 8*256
    int P0  = bs * 16;
    int nimg = P0 >> 12;
    int hw   = P0 & 4095;

    const float* xp = x + (size_t)nimg * CI * 4096 + hw + c16;

    f32x4 acc[4];
#pragma unroll
    for (int mt = 0; mt < 4; mt++) acc[mt] = f32x4{0.f, 0.f, 0.f, 0.f};

#pragma unroll
    for (int ks = 0; ks < 8; ks++) {
        int k0 = ks * 32 + lq * 8;
        float v[8];
#pragma unroll
        for (int j = 0; j < 8; j++) v[j] = xp[(size_t)(k0 + j) * 4096];
        bf16x8 xb;
#pragma unroll
        for (int j = 0; j < 8; j++) xb[j] = (short)f2bf(v[j]);
#pragma unroll
        for (int mt = 0; mt < 4; mt++) {
            bf16x8 wf = *(const bf16x8*)(wA + (mt * 16 + c16) * 256 + k0);
            acc[mt] = __builtin_amdgcn_mfma_f32_16x16x32_bf16(wf, xb, acc[mt], 0, 0, 0);
        }
    }

    unsigned short* cp = comp + (size_t)(P0 + c16) * 64;
#pragma unroll
    for (int mt = 0; mt < 4; mt++) {
        int och0 = mt * 16 + lq * 4;
        float4 bb = *reinterpret_cast<const float4*>(b_comp + och0);
        unsigned u0 = f2bf(acc[mt][0] + bb.x) | (f2bf(acc[mt][1] + bb.y) << 16);
        unsigned u1 = f2bf(acc[mt][2] + bb.z) | (f2bf(acc[mt][3] + bb.w) << 16);
        reinterpret_cast<uint2*>(cp + och0)[0] = uint2{u0, u1};
    }
}

// ---------------- kernel 2: 3x3 conv, B staged in LDS, packed-pair mask output ----------------
__global__ __launch_bounds__(256) void conv3x3_mfma(const unsigned short* __restrict__ comp,
                                                    const unsigned short* __restrict__ Bp,
                                                    const float* __restrict__ b_enc,
                                                    const float* __restrict__ zp,
                                                    unsigned* __restrict__ maskP) {
    __shared__ char Bs[2][7168];
    int tid = threadIdx.x;
    int wv  = tid >> 6;          // 0..3 (wave id)
    int l   = tid & 63;
    int c16 = l & 15;
    int lq  = l >> 4;
    int b   = blockIdx.x;
    int bs  = (b & 7) * 64 + (b >> 3);   // bijective: 512 = 8*64
    int nimg = bs >> 6;
    int h    = bs & 63;
    int w0   = wv * 16;

    const char* cbase = (const char*)(comp + (size_t)nimg * 4096 * 64);
    const char* zpb   = (const char*)zp;

#define STAGE(s_, buf_)                                                                   \
    {                                                                                     \
        const char* src_ = (const char*)Bp + (s_)*7168 + l * 16;                          \
        for (int inst_ = wv; inst_ < 7; inst_ += 4) {                                     \
            __builtin_amdgcn_global_load_lds(                                             \
                (const __attribute__((address_space(1))) void*)(src_ + inst_ * 1024),     \
                (__attribute__((address_space(3))) void*)(&Bs[buf_][inst_ * 1024]),       \
                16, 0, 0);                                                                \
        }                                                                                 \
    }

    f32x4 acc[7];
#pragma unroll
    for (int nt = 0; nt < 7; nt++) acc[nt] = f32x4{0.f, 0.f, 0.f, 0.f};

    const int dyt[9] = {-1, -1, -1, 0, 0, 0, 1, 1, 1};
    const int dxt[9] = {-1, 0, 1, -1, 0, 1, -1, 0, 1};

    STAGE(0, 0);
    __syncthreads();

#pragma unroll
    for (int s = 0; s < 18; s++) {
        int cur = s & 1;
        if (s < 17) STAGE(s + 1, cur ^ 1);

        int tap = s >> 1, half = s & 1;
        int hh = h + dyt[tap];
        int ww = w0 + c16 + dxt[tap];
        const char* ap = ((unsigned)hh < 64u && (unsigned)ww < 64u)
                             ? cbase + (hh * 64 + ww) * 128 : zpb;
        bf16x8 a = *(const bf16x8*)(ap + lq * 16 + half * 64);

        bf16x8 bf[7];
#pragma unroll
        for (int nt = 0; nt < 7; nt++)
            bf[nt] = *(const bf16x8*)(&Bs[cur][(lq * 112 + nt * 16 + c16) * 16]);
#pragma unroll
        for (int nt = 0; nt < 7; nt++)
            acc[nt] = __builtin_amdgcn_mfma_f32_16x16x32_bf16(a, bf[nt], acc[nt], 0, 0, 0);

        __syncthreads();
    }
#undef STAGE

    float bias[7];
#pragma unroll
    for (int nt = 0; nt < 7; nt++) {
        int n = nt * 16 + c16;
        bias[nt] = (n < 100) ? b_enc[n] : 0.f;
    }
    int nvalid = (c16 < 4) ? 7 : 6;

    unsigned* mbase = maskP + ((size_t)nimg * 64 + h) * 3200;

#pragma unroll
    for (int r = 0; r < 4; r++) {
        float v[7];
#pragma unroll
        for (int nt = 0; nt < 7; nt++) v[nt] = acc[nt][r] + bias[nt];
        float m = v[0];
#pragma unroll
        for (int nt = 1; nt < 7; nt++) if (nt < nvalid) m = fmaxf(m, v[nt]);
        m = fmaxf(m, __shfl_xor(m, 4));
        m = fmaxf(m, __shfl_xor(m, 8));
        float e[7];
        float s = 0.f;
#pragma unroll
        for (int nt = 0; nt < 7; nt++) {
            e[nt] = (nt < nvalid) ? __expf(v[nt] - m) : 0.f;
            s += e[nt];
        }
        s += __shfl_xor(s, 4);
        s += __shfl_xor(s, 8);
        float inv = 1.f / s;
        int wpix = w0 + lq * 4 + r;
        // pack lane-pair (n, n+1): same pixel (pixel depends only on lq,r), n = nt*16+c16
#pragma unroll
        for (int nt = 0; nt < 7; nt++) {
            float mine = (nt < nvalid) ? e[nt] * inv : 0.f;
            float part = __shfl_xor(mine, 1);
            if (((c16 & 1) == 0) && (nt * 16 + c16) < 100) {
                unsigned pk = cvt_pk_bf16(mine, part);
                mbase[(nt * 8 + (c16 >> 1)) * 64 + wpix] = pk;
            }
        }
    }
}

// ---------------- kernel 3: reassembly (merged sp rows, packed bpermute) ----------------
// Block produces BOTH output rows (2h, 2h+1), all 4 subpixels: DS + x-loads serve 2x
// the output vs the split version. mask: 50 packed uints -> 100 f32 regs, boundary folded.
__global__ __launch_bounds__(256) void reassemble(const float* __restrict__ x,
                                                  const unsigned* __restrict__ maskP,
                                                  float* __restrict__ out) {
    int lane = threadIdx.x & 63;       // = w
    int cq   = threadIdx.x >> 6;       // 0..3, wave-uniform
    int b    = blockIdx.x;
    int bs   = (b & 7) * 512 + (b >> 3);   // bijective: 4096 = 8*512
    int cgb  = bs & 7;
    int h    = (bs >> 3) & 63;
    int n    = bs >> 9;
    int c0   = cgb * 32 + cq * 8;

    const unsigned* mrow = maskP + ((size_t)n * 64 + h) * 3200 + lane;

    int   yy[5];
    float vmy[5], vmx[5];
#pragma unroll
    for (int d = 0; d < 5; d++) {
        int y  = h + d - 2;
        int xc = lane + d - 2;
        yy[d]  = min(max(y, 0), 63) * 64;
        vmy[d] = ((unsigned)y  < 64u) ? 1.f : 0.f;
        vmx[d] = ((unsigned)xc < 64u) ? 1.f : 0.f;
    }

    // msk[4t+{0,1,2,3}] = (row0col0,row0col1,row1col0,row1col1) for tap t, boundary-folded
    float msk[100];
#pragma unroll
    for (int t = 0; t < 25; t++) {
        float f = vmy[t / 5] * vmx[t % 5];
        unsigned u0 = mrow[(2 * t + 0) * 64];
        unsigned u1 = mrow[(2 * t + 1) * 64];
        msk[4 * t + 0] = bf_lo(u0) * f;
        msk[4 * t + 1] = bf_hi(u0) * f;
        msk[4 * t + 2] = bf_lo(u1) * f;
        msk[4 * t + 3] = bf_hi(u1) * f;
    }

    int idxm2 = ((lane - 2) & 63) << 2;
    int idxm1 = ((lane - 1) & 63) << 2;
    int idxp1 = ((lane + 1) & 63) << 2;
    int idxp2 = ((lane + 2) & 63) << 2;

    const float* xbase = x + ((size_t)(n * CI + c0)) * 4096 + lane;
    float*       obase = out + ((size_t)(n * CI + c0) * 128 + 2 * h) * 128 + 2 * lane;

    float ra[5], rb[5];
    unsigned pk[5];
#pragma unroll
    for (int d = 0; d < 5; d++) {
        ra[d] = xbase[yy[d]];
        rb[d] = xbase[4096 + yy[d]];
        pk[d] = cvt_pk_bf16(ra[d], rb[d]);
    }

    for (int p = 0; p < 4; p++) {
        const float* xn = xbase + (size_t)((p < 3) ? (2 * p + 2) : 0) * 4096;
        float na[5], nb[5];
#pragma unroll
        for (int d = 0; d < 5; d++) {
            na[d] = xn[yy[d]];
            nb[d] = xn[4096 + yy[d]];
        }

        // acc: a=chA, b=chB; [row(2)][col(2)]
        float a00 = 0.f, a01 = 0.f, a10 = 0.f, a11 = 0.f;
        float b00 = 0.f, b01 = 0.f, b10 = 0.f, b11 = 0.f;
#pragma unroll
        for (int d = 0; d < 5; d++) {
            int pv = (int)pk[d];
            int sm2 = __builtin_amdgcn_ds_bpermute(idxm2, pv);
            int sm1 = __builtin_amdgcn_ds_bpermute(idxm1, pv);
            int sp1 = __builtin_amdgcn_ds_bpermute(idxp1, pv);
            int sp2 = __builtin_amdgcn_ds_bpermute(idxp2, pv);
            float av[5], bv[5];
            av[0] = bf_lo((unsigned)sm2); bv[0] = bf_hi((unsigned)sm2);
            av[1] = bf_lo((unsigned)sm1); bv[1] = bf_hi((unsigned)sm1);
            av[2] = ra[d];                bv[2] = rb[d];
            av[3] = bf_lo((unsigned)sp1); bv[3] = bf_hi((unsigned)sp1);
            av[4] = bf_lo((unsigned)sp2); bv[4] = bf_hi((unsigned)sp2);
            const float* mk = msk + d * 20;
#pragma unroll
            for (int k = 0; k < 5; k++) {
                float m0 = mk[4 * k + 0], m1 = mk[4 * k + 1];
                float m2 = mk[4 * k + 2], m3 = mk[4 * k + 3];
                a00 += m0 * av[k]; a01 += m1 * av[k];
                a10 += m2 * av[k]; a11 += m3 * av[k];
                b00 += m0 * bv[k]; b01 += m1 * bv[k];
                b10 += m2 * bv[k]; b11 += m3 * bv[k];
            }
        }
        float* opa = obase + (size_t)(2 * p) * 16384;
        float* opb = opa + 16384;
        reinterpret_cast<float2*>(opa)[0]       = make_float2(a00, a01);
        reinterpret_cast<float2*>(opa + 128)[0] = make_float2(a10, a11);
        reinterpret_cast<float2*>(opb)[0]       = make_float2(b00, b01);
        reinterpret_cast<float2*>(opb + 128)[0] = make_float2(b10, b11);

#pragma unroll
        for (int d = 0; d < 5; d++) {
            ra[d] = na[d];
            rb[d] = nb[d];
            pk[d] = cvt_pk_bf16(na[d], nb[d]);
        }
    }
}

extern "C" void kernel_launch(void* const* d_in, const int* in_sizes, int n_in,
                              void* d_out, int out_size, void* d_ws, size_t ws_size,
                              hipStream_t stream) {
    const float* x      = (const float*)d_in[0];
    const float* w_comp = (const float*)d_in[1];
    const float* b_comp = (const float*)d_in[2];
    const float* w_enc  = (const float*)d_in[3];
    const float* b_enc  = (const float*)d_in[4];
    float* out = (float*)d_out;

    // workspace layout (bytes)
    char* ws = (char*)d_ws;
    float*          zp    = (float*)(ws + 0);                 // 256 B zeros
    unsigned short* wA    = (unsigned short*)(ws + 256);      // 32768 B
    unsigned short* Bp    = (unsigned short*)(ws + 33024);    // 129024 B
    unsigned short* comp  = (unsigned short*)(ws + 162048);   // 4 MB
    unsigned*       maskP = (unsigned*)(ws + 4356352);        // 8*64*50*64*4 = 6.55 MB
    // total ~11 MB

    prep_weights<<<252, 256, 0, stream>>>(w_comp, w_enc, wA, Bp, zp);
    conv1x1_mfma<<<2048, 64, 0, stream>>>(x, wA, b_comp, comp);
    conv3x3_mfma<<<512, 256, 0, stream>>>(comp, Bp, b_enc, zp, maskP);
    reassemble<<<4096, 256, 0, stream>>>(x, maskP, out);
}

// Round 11
// 70.613 us; speedup vs baseline: 3.5468x; 1.0899x over previous
//
#include <hip/hip_runtime.h>

// CARAFE: x(8,256,64,64) fp32
//   -> conv1x1 (256->64) as swapped-operand bf16 MFMA -> comp bf16 NHWC
//   -> conv3x3 (64->100) bf16 MFMA, B staged in LDS (5-step phases) + fused softmax, packed mask
//   -> reassembly (merged subpixel rows, packed bpermute, 16ch/thread) -> out fp32
// K=5, G=1, S=2.
// maskP layout: [nimg][h][n2(50)][w] uint, n2=2t+spq, pair=(sp=2spq, sp=2spq+1) bf16 (lo,hi).

#define CI 256

typedef __attribute__((ext_vector_type(8))) short bf16x8;
typedef __attribute__((ext_vector_type(4))) float f32x4;

__device__ inline unsigned short f2bf(float f) {
    unsigned u = __float_as_uint(f);
    unsigned r = (u + 0x7FFF + ((u >> 16) & 1)) >> 16;
    return (unsigned short)r;
}

__device__ inline unsigned cvt_pk_bf16(float lo, float hi) {
    unsigned r;
    asm("v_cvt_pk_bf16_f32 %0, %1, %2" : "=v"(r) : "v"(lo), "v"(hi));
    return r;
}

__device__ inline float bf_lo(unsigned u) { return __int_as_float(u << 16); }
__device__ inline float bf_hi(unsigned u) { return __int_as_float(u & 0xffff0000u); }

// ---------------- kernel 0: weight prep ----------------
__global__ __launch_bounds__(256) void prep_weights(const float* __restrict__ w_comp,
                                                    const float* __restrict__ w_enc,
                                                    unsigned short* __restrict__ wA,
                                                    unsigned short* __restrict__ Bp,
                                                    float* __restrict__ zp) {
    int i = blockIdx.x * 256 + threadIdx.x;
    if (i < 64) zp[i] = 0.f;
    if (i < 64 * 256) wA[i] = f2bf(w_comp[i]);
    if (i < 72 * 112 * 8) {
        int j = i & 7;
        int n = (i >> 3) % 112;
        int g = i / (112 * 8);
        int k = g * 8 + j;
        int tap = k >> 6;
        int c = k & 63;
        float v = (n < 100) ? w_enc[n * 576 + c * 9 + tap] : 0.f;
        Bp[i] = f2bf(v);
    }
}

// ---------------- kernel 1: 1x1 conv via MFMA, swapped operands ----------------
__global__ __launch_bounds__(64) void conv1x1_mfma(const float* __restrict__ x,
                                                   const unsigned short* __restrict__ wA,
                                                   const float* __restrict__ b_comp,
                                                   unsigned short* __restrict__ comp) {
    int l   = threadIdx.x;
    int c16 = l & 15;
    int lq  = l >> 4;
    int b   = blockIdx.x;
    int bs  = (b & 7) * 256 + (b >> 3);   // bijective: 2048 = 8*256
    int P0  = bs * 16;
    int nimg = P0 >> 12;
    int hw   = P0 & 4095;

    const float* xp = x + (size_t)nimg * CI * 4096 + hw + c16;

    f32x4 acc[4];
#pragma unroll
    for (int mt = 0; mt < 4; mt++) acc[mt] = f32x4{0.f, 0.f, 0.f, 0.f};

#pragma unroll
    for (int ks = 0; ks < 8; ks++) {
        int k0 = ks * 32 + lq * 8;
        float v[8];
#pragma unroll
        for (int j = 0; j < 8; j++) v[j] = xp[(size_t)(k0 + j) * 4096];
        bf16x8 xb;
#pragma unroll
        for (int j = 0; j < 8; j++) xb[j] = (short)f2bf(v[j]);
#pragma unroll
        for (int mt = 0; mt < 4; mt++) {
            bf16x8 wf = *(const bf16x8*)(wA + (mt * 16 + c16) * 256 + k0);
            acc[mt] = __builtin_amdgcn_mfma_f32_16x16x32_bf16(wf, xb, acc[mt], 0, 0, 0);
        }
    }

    unsigned short* cp = comp + (size_t)(P0 + c16) * 64;
#pragma unroll
    for (int mt = 0; mt < 4; mt++) {
        int och0 = mt * 16 + lq * 4;
        float4 bb = *reinterpret_cast<const float4*>(b_comp + och0);
        unsigned u0 = f2bf(acc[mt][0] + bb.x) | (f2bf(acc[mt][1] + bb.y) << 16);
        unsigned u1 = f2bf(acc[mt][2] + bb.z) | (f2bf(acc[mt][3] + bb.w) << 16);
        reinterpret_cast<uint2*>(cp + och0)[0] = uint2{u0, u1};
    }
}

// ---------------- kernel 2: 3x3 conv, B staged in LDS (5 K-steps/phase) ----------------
// Block = 4 waves = one row (64 px). K=576 in 18 sub-steps; staged 5 steps (35.8KB)
// per phase, double-buffered (71.7KB LDS) -> 5 barriers instead of 18.
__global__ __launch_bounds__(256) void conv3x3_mfma(const unsigned short* __restrict__ comp,
                                                    const unsigned short* __restrict__ Bp,
                                                    const float* __restrict__ b_enc,
                                                    const float* __restrict__ zp,
                                                    unsigned* __restrict__ maskP) {
    __shared__ char Bs[2][5 * 7168];
    int tid = threadIdx.x;
    int wv  = tid >> 6;          // 0..3 (wave id)
    int l   = tid & 63;
    int c16 = l & 15;
    int lq  = l >> 4;
    int b   = blockIdx.x;
    int bs  = (b & 7) * 64 + (b >> 3);   // bijective: 512 = 8*64
    int nimg = bs >> 6;
    int h    = bs & 63;
    int w0   = wv * 16;

    const char* cbase = (const char*)(comp + (size_t)nimg * 4096 * 64);
    const char* zpb   = (const char*)zp;
    const char* Bpb   = (const char*)Bp;

    // stage steps [s0, s0+cnt) into buffer buf
#define STAGEPH(s0_, cnt_, buf_)                                                          \
    {                                                                                     \
        const char* src_ = Bpb + (s0_)*7168 + l * 16;                                     \
        for (int inst_ = wv; inst_ < 7 * (cnt_); inst_ += 4) {                            \
            __builtin_amdgcn_global_load_lds(                                             \
                (const __attribute__((address_space(1))) void*)(src_ + inst_ * 1024),     \
                (__attribute__((address_space(3))) void*)(&Bs[buf_][inst_ * 1024]),       \
                16, 0, 0);                                                                \
        }                                                                                 \
    }

    f32x4 acc[7];
#pragma unroll
    for (int nt = 0; nt < 7; nt++) acc[nt] = f32x4{0.f, 0.f, 0.f, 0.f};

    const int dyt[9] = {-1, -1, -1, 0, 0, 0, 1, 1, 1};
    const int dxt[9] = {-1, 0, 1, -1, 0, 1, -1, 0, 1};

    STAGEPH(0, 5, 0);
    __syncthreads();   // Bs[0] ready

#pragma unroll
    for (int ph = 0; ph < 4; ph++) {
        int s0  = ph * 5;
        int cnt = (s0 + 5 <= 18) ? 5 : (18 - s0);
        int cur = ph & 1;
        // issue next phase's stage first (overlaps with compute below)
        if (ph < 3) {
            int ns0  = s0 + 5;
            int ncnt = (ns0 + 5 <= 18) ? 5 : (18 - ns0);
            STAGEPH(ns0, ncnt, cur ^ 1);
        }
        for (int ss = 0; ss < cnt; ss++) {
            int s = s0 + ss;
            int tap = s >> 1, half = s & 1;
            int hh = h + dyt[tap];
            int ww = w0 + c16 + dxt[tap];
            const char* ap = ((unsigned)hh < 64u && (unsigned)ww < 64u)
                                 ? cbase + (hh * 64 + ww) * 128 : zpb;
            bf16x8 a = *(const bf16x8*)(ap + lq * 16 + half * 64);

            bf16x8 bf[7];
#pragma unroll
            for (int nt = 0; nt < 7; nt++)
                bf[nt] = *(const bf16x8*)(&Bs[cur][ss * 7168 + (lq * 112 + nt * 16 + c16) * 16]);
#pragma unroll
            for (int nt = 0; nt < 7; nt++)
                acc[nt] = __builtin_amdgcn_mfma_f32_16x16x32_bf16(a, bf[nt], acc[nt], 0, 0, 0);
        }
        __syncthreads();   // next buffer staged; this buffer free for overwrite
    }
#undef STAGEPH

    float bias[7];
#pragma unroll
    for (int nt = 0; nt < 7; nt++) {
        int n = nt * 16 + c16;
        bias[nt] = (n < 100) ? b_enc[n] : 0.f;
    }
    int nvalid = (c16 < 4) ? 7 : 6;

    unsigned* mbase = maskP + ((size_t)nimg * 64 + h) * 3200;

#pragma unroll
    for (int r = 0; r < 4; r++) {
        float v[7];
#pragma unroll
        for (int nt = 0; nt < 7; nt++) v[nt] = acc[nt][r] + bias[nt];
        float m = v[0];
#pragma unroll
        for (int nt = 1; nt < 7; nt++) if (nt < nvalid) m = fmaxf(m, v[nt]);
        m = fmaxf(m, __shfl_xor(m, 4));
        m = fmaxf(m, __shfl_xor(m, 8));
        float e[7];
        float s = 0.f;
#pragma unroll
        for (int nt = 0; nt < 7; nt++) {
            e[nt] = (nt < nvalid) ? __expf(v[nt] - m) : 0.f;
            s += e[nt];
        }
        s += __shfl_xor(s, 4);
        s += __shfl_xor(s, 8);
        float inv = 1.f / s;
        int wpix = w0 + lq * 4 + r;
#pragma unroll
        for (int nt = 0; nt < 7; nt++) {
            float mine = (nt < nvalid) ? e[nt] * inv : 0.f;
            float part = __shfl_xor(mine, 1);
            if (((c16 & 1) == 0) && (nt * 16 + c16) < 100) {
                unsigned pk = cvt_pk_bf16(mine, part);
                mbase[(nt * 8 + (c16 >> 1)) * 64 + wpix] = pk;
            }
        }
    }
}

// ---------------- kernel 3: reassembly (merged sp rows, 16 ch/thread) ----------------
// Block produces both output rows, all 4 subpixels, 64 channels (16/thread): the
// per-(n,h) mask load/unpack + window setup amortize over 2x the channels vs R10.
__global__ __launch_bounds__(256) void reassemble(const float* __restrict__ x,
                                                  const unsigned* __restrict__ maskP,
                                                  float* __restrict__ out) {
    int lane = threadIdx.x & 63;       // = w
    int cq   = threadIdx.x >> 6;       // 0..3, wave-uniform
    int b    = blockIdx.x;
    int bs   = (b & 7) * 256 + (b >> 3);   // bijective: 2048 = 8*256
    int cgb  = bs & 3;
    int h    = (bs >> 2) & 63;
    int n    = bs >> 8;
    int c0   = cgb * 64 + cq * 16;

    const unsigned* mrow = maskP + ((size_t)n * 64 + h) * 3200 + lane;

    int   yy[5];
    float vmy[5], vmx[5];
#pragma unroll
    for (int d = 0; d < 5; d++) {
        int y  = h + d - 2;
        int xc = lane + d - 2;
        yy[d]  = min(max(y, 0), 63) * 64;
        vmy[d] = ((unsigned)y  < 64u) ? 1.f : 0.f;
        vmx[d] = ((unsigned)xc < 64u) ? 1.f : 0.f;
    }

    // msk[4t+{0,1,2,3}] = (row0col0,row0col1,row1col0,row1col1) for tap t, boundary-folded
    float msk[100];
#pragma unroll
    for (int t = 0; t < 25; t++) {
        float f = vmy[t / 5] * vmx[t % 5];
        unsigned u0 = mrow[(2 * t + 0) * 64];
        unsigned u1 = mrow[(2 * t + 1) * 64];
        msk[4 * t + 0] = bf_lo(u0) * f;
        msk[4 * t + 1] = bf_hi(u0) * f;
        msk[4 * t + 2] = bf_lo(u1) * f;
        msk[4 * t + 3] = bf_hi(u1) * f;
    }

    int idxm2 = ((lane - 2) & 63) << 2;
    int idxm1 = ((lane - 1) & 63) << 2;
    int idxp1 = ((lane + 1) & 63) << 2;
    int idxp2 = ((lane + 2) & 63) << 2;

    const float* xbase = x + ((size_t)(n * CI + c0)) * 4096 + lane;
    float*       obase = out + ((size_t)(n * CI + c0) * 128 + 2 * h) * 128 + 2 * lane;

    float ra[5], rb[5];
    unsigned pk[5];
#pragma unroll
    for (int d = 0; d < 5; d++) {
        ra[d] = xbase[yy[d]];
        rb[d] = xbase[4096 + yy[d]];
        pk[d] = cvt_pk_bf16(ra[d], rb[d]);
    }

    for (int p = 0; p < 8; p++) {
        const float* xn = xbase + (size_t)((p < 7) ? (2 * p + 2) : 0) * 4096;
        float na[5], nb[5];
#pragma unroll
        for (int d = 0; d < 5; d++) {
            na[d] = xn[yy[d]];
            nb[d] = xn[4096 + yy[d]];
        }

        float a00 = 0.f, a01 = 0.f, a10 = 0.f, a11 = 0.f;
        float b00 = 0.f, b01 = 0.f, b10 = 0.f, b11 = 0.f;
#pragma unroll
        for (int d = 0; d < 5; d++) {
            int pv = (int)pk[d];
            int sm2 = __builtin_amdgcn_ds_bpermute(idxm2, pv);
            int sm1 = __builtin_amdgcn_ds_bpermute(idxm1, pv);
            int sp1 = __builtin_amdgcn_ds_bpermute(idxp1, pv);
            int sp2 = __builtin_amdgcn_ds_bpermute(idxp2, pv);
            float av[5], bv[5];
            av[0] = bf_lo((unsigned)sm2); bv[0] = bf_hi((unsigned)sm2);
            av[1] = bf_lo((unsigned)sm1); bv[1] = bf_hi((unsigned)sm1);
            av[2] = ra[d];                bv[2] = rb[d];
            av[3] = bf_lo((unsigned)sp1); bv[3] = bf_hi((unsigned)sp1);
            av[4] = bf_lo((unsigned)sp2); bv[4] = bf_hi((unsigned)sp2);
            const float* mk = msk + d * 20;
#pragma unroll
            for (int k = 0; k < 5; k++) {
                float m0 = mk[4 * k + 0], m1 = mk[4 * k + 1];
                float m2 = mk[4 * k + 2], m3 = mk[4 * k + 3];
                a00 += m0 * av[k]; a01 += m1 * av[k];
                a10 += m2 * av[k]; a11 += m3 * av[k];
                b00 += m0 * bv[k]; b01 += m1 * bv[k];
                b10 += m2 * bv[k]; b11 += m3 * bv[k];
            }
        }
        float* opa = obase + (size_t)(2 * p) * 16384;
        float* opb = opa + 16384;
        reinterpret_cast<float2*>(opa)[0]       = make_float2(a00, a01);
        reinterpret_cast<float2*>(opa + 128)[0] = make_float2(a10, a11);
        reinterpret_cast<float2*>(opb)[0]       = make_float2(b00, b01);
        reinterpret_cast<float2*>(opb + 128)[0] = make_float2(b10, b11);

#pragma unroll
        for (int d = 0; d < 5; d++) {
            ra[d] = na[d];
            rb[d] = nb[d];
            pk[d] = cvt_pk_bf16(na[d], nb[d]);
        }
    }
}

extern "C" void kernel_launch(void* const* d_in, const int* in_sizes, int n_in,
                              void* d_out, int out_size, void* d_ws, size_t ws_size,
                              hipStream_t stream) {
    const float* x      = (const float*)d_in[0];
    const float* w_comp = (const float*)d_in[1];
    const float* b_comp = (const float*)d_in[2];
    const float* w_enc  = (const float*)d_in[3];
    const float* b_enc  = (const float*)d_in[4];
    float* out = (float*)d_out;

    // workspace layout (bytes)
    char* ws = (char*)d_ws;
    float*          zp    = (float*)(ws + 0);                 // 256 B zeros
    unsigned short* wA    = (unsigned short*)(ws + 256);      // 32768 B
    unsigned short* Bp    = (unsigned short*)(ws + 33024);    // 129024 B
    unsigned short* comp  = (unsigned short*)(ws + 162048);   // 4 MB
    unsigned*       maskP = (unsigned*)(ws + 4356352);        // 6.55 MB
    // total ~11 MB

    prep_weights<<<252, 256, 0, stream>>>(w_comp, w_enc, wA, Bp, zp);
    conv1x1_mfma<<<2048, 64, 0, stream>>>(x, wA, b_comp, comp);
    conv3x3_mfma<<<512, 256, 0, stream>>>(comp, Bp, b_enc, zp, maskP);
    reassemble<<<2048, 256, 0, stream>>>(x, maskP, out);
}

// Round 12
// 69.455 us; speedup vs baseline: 3.6060x; 1.0167x over previous
//
#include <hip/hip_runtime.h>

// CARAFE: x(8,256,64,64) fp32
//   -> conv1x1 (256->64) as swapped-operand bf16 MFMA -> comp bf16 NHWC
//   -> conv3x3 (64->100) bf16 MFMA, B staged in LDS (5-step phases) + fused softmax, packed mask
//   -> reassembly (merged sp rows, packed bpermute, v_pk_fma_f32 inner loop) -> out fp32
// K=5, G=1, S=2.
// maskP layout: [nimg][h][n2(50)][w] uint, n2=2t+spq, pair=(sp=2spq, sp=2spq+1) bf16 (lo,hi).

#define CI 256

typedef __attribute__((ext_vector_type(8))) short bf16x8;
typedef __attribute__((ext_vector_type(4))) float f32x4;
typedef __attribute__((ext_vector_type(2))) float f32x2;

__device__ inline unsigned short f2bf(float f) {
    unsigned u = __float_as_uint(f);
    unsigned r = (u + 0x7FFF + ((u >> 16) & 1)) >> 16;
    return (unsigned short)r;
}

__device__ inline unsigned cvt_pk_bf16(float lo, float hi) {
    unsigned r;
    asm("v_cvt_pk_bf16_f32 %0, %1, %2" : "=v"(r) : "v"(lo), "v"(hi));
    return r;
}

__device__ inline float bf_lo(unsigned u) { return __int_as_float(u << 16); }
__device__ inline float bf_hi(unsigned u) { return __int_as_float(u & 0xffff0000u); }

// acc.lo += m.lo * s.lo ; acc.hi += m.hi * s.lo   (broadcast s.lo)
__device__ inline void pk_fma_lo(f32x2& acc, f32x2 m, f32x2 s) {
    asm("v_pk_fma_f32 %0, %1, %2, %0 op_sel_hi:[1,0,1]" : "+v"(acc) : "v"(m), "v"(s));
}
// acc.lo += m.lo * s.hi ; acc.hi += m.hi * s.hi   (broadcast s.hi)
__device__ inline void pk_fma_hi(f32x2& acc, f32x2 m, f32x2 s) {
    asm("v_pk_fma_f32 %0, %1, %2, %0 op_sel:[0,1,0] op_sel_hi:[1,1,1]" : "+v"(acc) : "v"(m), "v"(s));
}

// ---------------- kernel 0: weight prep ----------------
__global__ __launch_bounds__(256) void prep_weights(const float* __restrict__ w_comp,
                                                    const float* __restrict__ w_enc,
                                                    unsigned short* __restrict__ wA,
                                                    unsigned short* __restrict__ Bp,
                                                    float* __restrict__ zp) {
    int i = blockIdx.x * 256 + threadIdx.x;
    if (i < 64) zp[i] = 0.f;
    if (i < 64 * 256) wA[i] = f2bf(w_comp[i]);
    if (i < 72 * 112 * 8) {
        int j = i & 7;
        int n = (i >> 3) % 112;
        int g = i / (112 * 8);
        int k = g * 8 + j;
        int tap = k >> 6;
        int c = k & 63;
        float v = (n < 100) ? w_enc[n * 576 + c * 9 + tap] : 0.f;
        Bp[i] = f2bf(v);
    }
}

// ---------------- kernel 1: 1x1 conv via MFMA, swapped operands ----------------
__global__ __launch_bounds__(64) void conv1x1_mfma(const float* __restrict__ x,
                                                   const unsigned short* __restrict__ wA,
                                                   const float* __restrict__ b_comp,
                                                   unsigned short* __restrict__ comp) {
    int l   = threadIdx.x;
    int c16 = l & 15;
    int lq  = l >> 4;
    int b   = blockIdx.x;
    int bs  = (b & 7) * 256 + (b >> 3);   // bijective: 2048 = 8*256
    int P0  = bs * 16;
    int nimg = P0 >> 12;
    int hw   = P0 & 4095;

    const float* xp = x + (size_t)nimg * CI * 4096 + hw + c16;

    f32x4 acc[4];
#pragma unroll
    for (int mt = 0; mt < 4; mt++) acc[mt] = f32x4{0.f, 0.f, 0.f, 0.f};

#pragma unroll
    for (int ks = 0; ks < 8; ks++) {
        int k0 = ks * 32 + lq * 8;
        float v[8];
#pragma unroll
        for (int j = 0; j < 8; j++) v[j] = xp[(size_t)(k0 + j) * 4096];
        bf16x8 xb;
#pragma unroll
        for (int j = 0; j < 8; j++) xb[j] = (short)f2bf(v[j]);
#pragma unroll
        for (int mt = 0; mt < 4; mt++) {
            bf16x8 wf = *(const bf16x8*)(wA + (mt * 16 + c16) * 256 + k0);
            acc[mt] = __builtin_amdgcn_mfma_f32_16x16x32_bf16(wf, xb, acc[mt], 0, 0, 0);
        }
    }

    unsigned short* cp = comp + (size_t)(P0 + c16) * 64;
#pragma unroll
    for (int mt = 0; mt < 4; mt++) {
        int och0 = mt * 16 + lq * 4;
        float4 bb = *reinterpret_cast<const float4*>(b_comp + och0);
        unsigned u0 = f2bf(acc[mt][0] + bb.x) | (f2bf(acc[mt][1] + bb.y) << 16);
        unsigned u1 = f2bf(acc[mt][2] + bb.z) | (f2bf(acc[mt][3] + bb.w) << 16);
        reinterpret_cast<uint2*>(cp + och0)[0] = uint2{u0, u1};
    }
}

// ---------------- kernel 2: 3x3 conv, B staged in LDS (5 K-steps/phase) ----------------
__global__ __launch_bounds__(256) void conv3x3_mfma(const unsigned short* __restrict__ comp,
                                                    const unsigned short* __restrict__ Bp,
                                                    const float* __restrict__ b_enc,
                                                    const float* __restrict__ zp,
                                                    unsigned* __restrict__ maskP) {
    __shared__ char Bs[2][5 * 7168];
    int tid = threadIdx.x;
    int wv  = tid >> 6;          // 0..3 (wave id)
    int l   = tid & 63;
    int c16 = l & 15;
    int lq  = l >> 4;
    int b   = blockIdx.x;
    int bs  = (b & 7) * 64 + (b >> 3);   // bijective: 512 = 8*64
    int nimg = bs >> 6;
    int h    = bs & 63;
    int w0   = wv * 16;

    const char* cbase = (const char*)(comp + (size_t)nimg * 4096 * 64);
    const char* zpb   = (const char*)zp;
    const char* Bpb   = (const char*)Bp;

#define STAGEPH(s0_, cnt_, buf_)                                                          \
    {                                                                                     \
        const char* src_ = Bpb + (s0_)*7168 + l * 16;                                     \
        for (int inst_ = wv; inst_ < 7 * (cnt_); inst_ += 4) {                            \
            __builtin_amdgcn_global_load_lds(                                             \
                (const __attribute__((address_space(1))) void*)(src_ + inst_ * 1024),     \
                (__attribute__((address_space(3))) void*)(&Bs[buf_][inst_ * 1024]),       \
                16, 0, 0);                                                                \
        }                                                                                 \
    }

    f32x4 acc[7];
#pragma unroll
    for (int nt = 0; nt < 7; nt++) acc[nt] = f32x4{0.f, 0.f, 0.f, 0.f};

    const int dyt[9] = {-1, -1, -1, 0, 0, 0, 1, 1, 1};
    const int dxt[9] = {-1, 0, 1, -1, 0, 1, -1, 0, 1};

    STAGEPH(0, 5, 0);
    __syncthreads();

#pragma unroll
    for (int ph = 0; ph < 4; ph++) {
        int s0  = ph * 5;
        int cnt = (s0 + 5 <= 18) ? 5 : (18 - s0);
        int cur = ph & 1;
        if (ph < 3) {
            int ns0  = s0 + 5;
            int ncnt = (ns0 + 5 <= 18) ? 5 : (18 - ns0);
            STAGEPH(ns0, ncnt, cur ^ 1);
        }
        for (int ss = 0; ss < cnt; ss++) {
            int s = s0 + ss;
            int tap = s >> 1, half = s & 1;
            int hh = h + dyt[tap];
            int ww = w0 + c16 + dxt[tap];
            const char* ap = ((unsigned)hh < 64u && (unsigned)ww < 64u)
                                 ? cbase + (hh * 64 + ww) * 128 : zpb;
            bf16x8 a = *(const bf16x8*)(ap + lq * 16 + half * 64);

            bf16x8 bf[7];
#pragma unroll
            for (int nt = 0; nt < 7; nt++)
                bf[nt] = *(const bf16x8*)(&Bs[cur][ss * 7168 + (lq * 112 + nt * 16 + c16) * 16]);
#pragma unroll
            for (int nt = 0; nt < 7; nt++)
                acc[nt] = __builtin_amdgcn_mfma_f32_16x16x32_bf16(a, bf[nt], acc[nt], 0, 0, 0);
        }
        __syncthreads();
    }
#undef STAGEPH

    float bias[7];
#pragma unroll
    for (int nt = 0; nt < 7; nt++) {
        int n = nt * 16 + c16;
        bias[nt] = (n < 100) ? b_enc[n] : 0.f;
    }
    int nvalid = (c16 < 4) ? 7 : 6;

    unsigned* mbase = maskP + ((size_t)nimg * 64 + h) * 3200;

#pragma unroll
    for (int r = 0; r < 4; r++) {
        float v[7];
#pragma unroll
        for (int nt = 0; nt < 7; nt++) v[nt] = acc[nt][r] + bias[nt];
        float m = v[0];
#pragma unroll
        for (int nt = 1; nt < 7; nt++) if (nt < nvalid) m = fmaxf(m, v[nt]);
        m = fmaxf(m, __shfl_xor(m, 4));
        m = fmaxf(m, __shfl_xor(m, 8));
        float e[7];
        float s = 0.f;
#pragma unroll
        for (int nt = 0; nt < 7; nt++) {
            e[nt] = (nt < nvalid) ? __expf(v[nt] - m) : 0.f;
            s += e[nt];
        }
        s += __shfl_xor(s, 4);
        s += __shfl_xor(s, 8);
        float inv = 1.f / s;
        int wpix = w0 + lq * 4 + r;
#pragma unroll
        for (int nt = 0; nt < 7; nt++) {
            float mine = (nt < nvalid) ? e[nt] * inv : 0.f;
            float part = __shfl_xor(mine, 1);
            if (((c16 & 1) == 0) && (nt * 16 + c16) < 100) {
                unsigned pk = cvt_pk_bf16(mine, part);
                mbase[(nt * 8 + (c16 >> 1)) * 64 + wpix] = pk;
            }
        }
    }
}

// ---------------- kernel 3: reassembly (merged sp rows, 16 ch/thread, pk_fma) ----------------
// Accumulators paired (col0,col1) as f32x2; x channel-pair (chA,chB) in one f32x2;
// v_pk_fma_f32 with op_sel broadcast -> 4 pk-FMAs per (k,d) instead of 8 scalar FMAs.
__global__ __launch_bounds__(256) void reassemble(const float* __restrict__ x,
                                                  const unsigned* __restrict__ maskP,
                                                  float* __restrict__ out) {
    int lane = threadIdx.x & 63;       // = w
    int cq   = threadIdx.x >> 6;       // 0..3, wave-uniform
    int b    = blockIdx.x;
    int bs   = (b & 7) * 256 + (b >> 3);   // bijective: 2048 = 8*256
    int cgb  = bs & 3;
    int h    = (bs >> 2) & 63;
    int n    = bs >> 8;
    int c0   = cgb * 64 + cq * 16;

    const unsigned* mrow = maskP + ((size_t)n * 64 + h) * 3200 + lane;

    int   yy[5];
    float vmy[5], vmx[5];
#pragma unroll
    for (int d = 0; d < 5; d++) {
        int y  = h + d - 2;
        int xc = lane + d - 2;
        yy[d]  = min(max(y, 0), 63) * 64;
        vmy[d] = ((unsigned)y  < 64u) ? 1.f : 0.f;
        vmx[d] = ((unsigned)xc < 64u) ? 1.f : 0.f;
    }

    // msk2[2t]   = (row0col0,row0col1) * fold,  msk2[2t+1] = (row1col0,row1col1) * fold
    f32x2 msk2[50];
#pragma unroll
    for (int t = 0; t < 25; t++) {
        float f = vmy[t / 5] * vmx[t % 5];
        unsigned u0 = mrow[(2 * t + 0) * 64];
        unsigned u1 = mrow[(2 * t + 1) * 64];
        f32x2 m01, m23;
        m01.x = bf_lo(u0); m01.y = bf_hi(u0);
        m23.x = bf_lo(u1); m23.y = bf_hi(u1);
        msk2[2 * t + 0] = m01 * f;
        msk2[2 * t + 1] = m23 * f;
    }

    int idxm2 = ((lane - 2) & 63) << 2;
    int idxm1 = ((lane - 1) & 63) << 2;
    int idxp1 = ((lane + 1) & 63) << 2;
    int idxp2 = ((lane + 2) & 63) << 2;

    const float* xbase = x + ((size_t)(n * CI + c0)) * 4096 + lane;
    float*       obase = out + ((size_t)(n * CI + c0) * 128 + 2 * h) * 128 + 2 * lane;

    float ra[5], rb[5];
    unsigned pk[5];
#pragma unroll
    for (int d = 0; d < 5; d++) {
        ra[d] = xbase[yy[d]];
        rb[d] = xbase[4096 + yy[d]];
        pk[d] = cvt_pk_bf16(ra[d], rb[d]);
    }

    for (int p = 0; p < 8; p++) {
        const float* xn = xbase + (size_t)((p < 7) ? (2 * p + 2) : 0) * 4096;
        float na[5], nb[5];
#pragma unroll
        for (int d = 0; d < 5; d++) {
            na[d] = xn[yy[d]];
            nb[d] = xn[4096 + yy[d]];
        }

        f32x2 A0 = {0.f, 0.f}, A1 = {0.f, 0.f};   // rows 0,1 for channel A (cols packed)
        f32x2 B0 = {0.f, 0.f}, B1 = {0.f, 0.f};   // rows 0,1 for channel B
#pragma unroll
        for (int d = 0; d < 5; d++) {
            int pv = (int)pk[d];
            int sm2 = __builtin_amdgcn_ds_bpermute(idxm2, pv);
            int sm1 = __builtin_amdgcn_ds_bpermute(idxm1, pv);
            int sp1 = __builtin_amdgcn_ds_bpermute(idxp1, pv);
            int sp2 = __builtin_amdgcn_ds_bpermute(idxp2, pv);
            f32x2 s[5];
            s[0].x = bf_lo((unsigned)sm2); s[0].y = bf_hi((unsigned)sm2);
            s[1].x = bf_lo((unsigned)sm1); s[1].y = bf_hi((unsigned)sm1);
            s[2].x = ra[d];                s[2].y = rb[d];
            s[3].x = bf_lo((unsigned)sp1); s[3].y = bf_hi((unsigned)sp1);
            s[4].x = bf_lo((unsigned)sp2); s[4].y = bf_hi((unsigned)sp2);
            const f32x2* mk2 = msk2 + d * 10;
#pragma unroll
            for (int k = 0; k < 5; k++) {
                pk_fma_lo(A0, mk2[2 * k + 0], s[k]);   // chA: rows 0
                pk_fma_lo(A1, mk2[2 * k + 1], s[k]);   // chA: rows 1
                pk_fma_hi(B0, mk2[2 * k + 0], s[k]);   // chB: rows 0
                pk_fma_hi(B1, mk2[2 * k + 1], s[k]);   // chB: rows 1
            }
        }
        float* opa = obase + (size_t)(2 * p) * 16384;
        float* opb = opa + 16384;
        *reinterpret_cast<f32x2*>(opa)       = A0;
        *reinterpret_cast<f32x2*>(opa + 128) = A1;
        *reinterpret_cast<f32x2*>(opb)       = B0;
        *reinterpret_cast<f32x2*>(opb + 128) = B1;

#pragma unroll
        for (int d = 0; d < 5; d++) {
            ra[d] = na[d];
            rb[d] = nb[d];
            pk[d] = cvt_pk_bf16(na[d], nb[d]);
        }
    }
}

extern "C" void kernel_launch(void* const* d_in, const int* in_sizes, int n_in,
                              void* d_out, int out_size, void* d_ws, size_t ws_size,
                              hipStream_t stream) {
    const float* x      = (const float*)d_in[0];
    const float* w_comp = (const float*)d_in[1];
    const float* b_comp = (const float*)d_in[2];
    const float* w_enc  = (const float*)d_in[3];
    const float* b_enc  = (const float*)d_in[4];
    float* out = (float*)d_out;

    // workspace layout (bytes)
    char* ws = (char*)d_ws;
    float*          zp    = (float*)(ws + 0);                 // 256 B zeros
    unsigned short* wA    = (unsigned short*)(ws + 256);      // 32768 B
    unsigned short* Bp    = (unsigned short*)(ws + 33024);    // 129024 B
    unsigned short* comp  = (unsigned short*)(ws + 162048);   // 4 MB
    unsigned*       maskP = (unsigned*)(ws + 4356352);        // 6.55 MB
    // total ~11 MB

    prep_weights<<<252, 256, 0, stream>>>(w_comp, w_enc, wA, Bp, zp);
    conv1x1_mfma<<<2048, 64, 0, stream>>>(x, wA, b_comp, comp);
    conv3x3_mfma<<<512, 256, 0, stream>>>(comp, Bp, b_enc, zp, maskP);
    reassemble<<<2048, 256, 0, stream>>>(x, maskP, out);
}

// Round 13
// 68.677 us; speedup vs baseline: 3.6468x; 1.0113x over previous
//
#include <hip/hip_runtime.h>

// CARAFE: x(8,256,64,64) fp32
//   -> conv1x1 (256->64) swapped-operand bf16 MFMA (+ Bp prep in trailing blocks) -> comp bf16 NHWC
//   -> conv3x3 (64->100) bf16 MFMA, B staged in LDS (5-step phases) + fused softmax, packed mask
//   -> reassembly (merged sp rows, packed bpermute, pk_fma, nontemporal out) -> out fp32
// K=5, G=1, S=2.
// maskP layout: [nimg][h][n2(50)][w] uint, n2=2t+spq, pair=(sp=2spq, sp=2spq+1) bf16 (lo,hi).

#define CI 256

typedef __attribute__((ext_vector_type(8))) short bf16x8;
typedef __attribute__((ext_vector_type(4))) float f32x4;
typedef __attribute__((ext_vector_type(2))) float f32x2;

__device__ inline unsigned short f2bf(float f) {
    unsigned u = __float_as_uint(f);
    unsigned r = (u + 0x7FFF + ((u >> 16) & 1)) >> 16;
    return (unsigned short)r;
}

__device__ inline unsigned cvt_pk_bf16(float lo, float hi) {
    unsigned r;
    asm("v_cvt_pk_bf16_f32 %0, %1, %2" : "=v"(r) : "v"(lo), "v"(hi));
    return r;
}

__device__ inline float bf_lo(unsigned u) { return __int_as_float(u << 16); }
__device__ inline float bf_hi(unsigned u) { return __int_as_float(u & 0xffff0000u); }

// acc.lo += m.lo * s.lo ; acc.hi += m.hi * s.lo   (broadcast s.lo)
__device__ inline void pk_fma_lo(f32x2& acc, f32x2 m, f32x2 s) {
    asm("v_pk_fma_f32 %0, %1, %2, %0 op_sel_hi:[1,0,1]" : "+v"(acc) : "v"(m), "v"(s));
}
// acc.lo += m.lo * s.hi ; acc.hi += m.hi * s.hi   (broadcast s.hi)
__device__ inline void pk_fma_hi(f32x2& acc, f32x2 m, f32x2 s) {
    asm("v_pk_fma_f32 %0, %1, %2, %0 op_sel:[0,1,0] op_sel_hi:[1,1,1]" : "+v"(acc) : "v"(m), "v"(s));
}

__device__ inline void nt_store2(float* p, f32x2 v) {
    __builtin_nontemporal_store(__builtin_bit_cast(unsigned long long, v),
                                (unsigned long long*)p);
}

// ---------------- kernel 0: small prep (wA, zp only — conv1x1 reads these) ----------------
__global__ __launch_bounds__(256) void prep_small(const float* __restrict__ w_comp,
                                                  unsigned short* __restrict__ wA,
                                                  float* __restrict__ zp) {
    int i = blockIdx.x * 256 + threadIdx.x;
    if (i < 64) zp[i] = 0.f;
    if (i < 64 * 256) wA[i] = f2bf(w_comp[i]);
}

// ---------------- kernel 1: 1x1 conv via MFMA + Bp prep in trailing blocks ----------------
__global__ __launch_bounds__(64) void conv1x1_mfma(const float* __restrict__ x,
                                                   const unsigned short* __restrict__ wA,
                                                   const float* __restrict__ b_comp,
                                                   const float* __restrict__ w_enc,
                                                   unsigned short* __restrict__ comp,
                                                   unsigned short* __restrict__ Bp) {
    int l = threadIdx.x;
    int b = blockIdx.x;

    if (b >= 2048) {
        // Bp prep: k=g*8+j, tap=k>>6, c=k&63; Bp[g][n][j] (n<100 else 0)
        int idx = (b - 2048) * 64 + l;      // < 72*112*8 = 64512
        int j = idx & 7;
        int n = (idx >> 3) % 112;
        int g = idx / (112 * 8);
        int k = g * 8 + j;
        int tap = k >> 6;
        int c = k & 63;
        float v = (n < 100) ? w_enc[n * 576 + c * 9 + tap] : 0.f;
        Bp[idx] = f2bf(v);
        return;
    }

    int c16 = l & 15;
    int lq  = l >> 4;
    int bs  = (b & 7) * 256 + (b >> 3);   // bijective: 2048 = 8*256
    int P0  = bs * 16;
    int nimg = P0 >> 12;
    int hw   = P0 & 4095;

    const float* xp = x + (size_t)nimg * CI * 4096 + hw + c16;

    f32x4 acc[4];
#pragma unroll
    for (int mt = 0; mt < 4; mt++) acc[mt] = f32x4{0.f, 0.f, 0.f, 0.f};

#pragma unroll
    for (int ks = 0; ks < 8; ks++) {
        int k0 = ks * 32 + lq * 8;
        float v[8];
#pragma unroll
        for (int j = 0; j < 8; j++) v[j] = xp[(size_t)(k0 + j) * 4096];
        bf16x8 xb;
#pragma unroll
        for (int j = 0; j < 8; j++) xb[j] = (short)f2bf(v[j]);
#pragma unroll
        for (int mt = 0; mt < 4; mt++) {
            bf16x8 wf = *(const bf16x8*)(wA + (mt * 16 + c16) * 256 + k0);
            acc[mt] = __builtin_amdgcn_mfma_f32_16x16x32_bf16(wf, xb, acc[mt], 0, 0, 0);
        }
    }

    unsigned short* cp = comp + (size_t)(P0 + c16) * 64;
#pragma unroll
    for (int mt = 0; mt < 4; mt++) {
        int och0 = mt * 16 + lq * 4;
        float4 bb = *reinterpret_cast<const float4*>(b_comp + och0);
        unsigned u0 = f2bf(acc[mt][0] + bb.x) | (f2bf(acc[mt][1] + bb.y) << 16);
        unsigned u1 = f2bf(acc[mt][2] + bb.z) | (f2bf(acc[mt][3] + bb.w) << 16);
        reinterpret_cast<uint2*>(cp + och0)[0] = uint2{u0, u1};
    }
}

// ---------------- kernel 2: 3x3 conv, B staged in LDS (5 K-steps/phase) ----------------
__global__ __launch_bounds__(256) void conv3x3_mfma(const unsigned short* __restrict__ comp,
                                                    const unsigned short* __restrict__ Bp,
                                                    const float* __restrict__ b_enc,
                                                    const float* __restrict__ zp,
                                                    unsigned* __restrict__ maskP) {
    __shared__ char Bs[2][5 * 7168];
    int tid = threadIdx.x;
    int wv  = tid >> 6;          // 0..3 (wave id)
    int l   = tid & 63;
    int c16 = l & 15;
    int lq  = l >> 4;
    int b   = blockIdx.x;
    int bs  = (b & 7) * 64 + (b >> 3);   // bijective: 512 = 8*64
    int nimg = bs >> 6;
    int h    = bs & 63;
    int w0   = wv * 16;

    const char* cbase = (const char*)(comp + (size_t)nimg * 4096 * 64);
    const char* zpb   = (const char*)zp;
    const char* Bpb   = (const char*)Bp;

#define STAGEPH(s0_, cnt_, buf_)                                                          \
    {                                                                                     \
        const char* src_ = Bpb + (s0_)*7168 + l * 16;                                     \
        for (int inst_ = wv; inst_ < 7 * (cnt_); inst_ += 4) {                            \
            __builtin_amdgcn_global_load_lds(                                             \
                (const __attribute__((address_space(1))) void*)(src_ + inst_ * 1024),     \
                (__attribute__((address_space(3))) void*)(&Bs[buf_][inst_ * 1024]),       \
                16, 0, 0);                                                                \
        }                                                                                 \
    }

    f32x4 acc[7];
#pragma unroll
    for (int nt = 0; nt < 7; nt++) acc[nt] = f32x4{0.f, 0.f, 0.f, 0.f};

    const int dyt[9] = {-1, -1, -1, 0, 0, 0, 1, 1, 1};
    const int dxt[9] = {-1, 0, 1, -1, 0, 1, -1, 0, 1};

    STAGEPH(0, 5, 0);
    __syncthreads();

#pragma unroll
    for (int ph = 0; ph < 4; ph++) {
        int s0  = ph * 5;
        int cnt = (s0 + 5 <= 18) ? 5 : (18 - s0);
        int cur = ph & 1;
        if (ph < 3) {
            int ns0  = s0 + 5;
            int ncnt = (ns0 + 5 <= 18) ? 5 : (18 - ns0);
            STAGEPH(ns0, ncnt, cur ^ 1);
        }
        for (int ss = 0; ss < cnt; ss++) {
            int s = s0 + ss;
            int tap = s >> 1, half = s & 1;
            int hh = h + dyt[tap];
            int ww = w0 + c16 + dxt[tap];
            const char* ap = ((unsigned)hh < 64u && (unsigned)ww < 64u)
                                 ? cbase + (hh * 64 + ww) * 128 : zpb;
            bf16x8 a = *(const bf16x8*)(ap + lq * 16 + half * 64);

            bf16x8 bf[7];
#pragma unroll
            for (int nt = 0; nt < 7; nt++)
                bf[nt] = *(const bf16x8*)(&Bs[cur][ss * 7168 + (lq * 112 + nt * 16 + c16) * 16]);
#pragma unroll
            for (int nt = 0; nt < 7; nt++)
                acc[nt] = __builtin_amdgcn_mfma_f32_16x16x32_bf16(a, bf[nt], acc[nt], 0, 0, 0);
        }
        __syncthreads();
    }
#undef STAGEPH

    float bias[7];
#pragma unroll
    for (int nt = 0; nt < 7; nt++) {
        int n = nt * 16 + c16;
        bias[nt] = (n < 100) ? b_enc[n] : 0.f;
    }
    int nvalid = (c16 < 4) ? 7 : 6;

    unsigned* mbase = maskP + ((size_t)nimg * 64 + h) * 3200;

#pragma unroll
    for (int r = 0; r < 4; r++) {
        float v[7];
#pragma unroll
        for (int nt = 0; nt < 7; nt++) v[nt] = acc[nt][r] + bias[nt];
        float m = v[0];
#pragma unroll
        for (int nt = 1; nt < 7; nt++) if (nt < nvalid) m = fmaxf(m, v[nt]);
        m = fmaxf(m, __shfl_xor(m, 4));
        m = fmaxf(m, __shfl_xor(m, 8));
        float e[7];
        float s = 0.f;
#pragma unroll
        for (int nt = 0; nt < 7; nt++) {
            e[nt] = (nt < nvalid) ? __expf(v[nt] - m) : 0.f;
            s += e[nt];
        }
        s += __shfl_xor(s, 4);
        s += __shfl_xor(s, 8);
        float inv = 1.f / s;
        int wpix = w0 + lq * 4 + r;
#pragma unroll
        for (int nt = 0; nt < 7; nt++) {
            float mine = (nt < nvalid) ? e[nt] * inv : 0.f;
            float part = __shfl_xor(mine, 1);
            if (((c16 & 1) == 0) && (nt * 16 + c16) < 100) {
                unsigned pk = cvt_pk_bf16(mine, part);
                mbase[(nt * 8 + (c16 >> 1)) * 64 + wpix] = pk;
            }
        }
    }
}

// ---------------- kernel 3: reassembly (merged sp rows, pk_fma, nontemporal out) ----------------
__global__ __launch_bounds__(256) void reassemble(const float* __restrict__ x,
                                                  const unsigned* __restrict__ maskP,
                                                  float* __restrict__ out) {
    int lane = threadIdx.x & 63;       // = w
    int cq   = threadIdx.x >> 6;       // 0..3, wave-uniform
    int b    = blockIdx.x;
    int bs   = (b & 7) * 256 + (b >> 3);   // bijective: 2048 = 8*256
    int cgb  = bs & 3;
    int h    = (bs >> 2) & 63;
    int n    = bs >> 8;
    int c0   = cgb * 64 + cq * 16;

    const unsigned* mrow = maskP + ((size_t)n * 64 + h) * 3200 + lane;

    int   yy[5];
    float vmy[5], vmx[5];
#pragma unroll
    for (int d = 0; d < 5; d++) {
        int y  = h + d - 2;
        int xc = lane + d - 2;
        yy[d]  = min(max(y, 0), 63) * 64;
        vmy[d] = ((unsigned)y  < 64u) ? 1.f : 0.f;
        vmx[d] = ((unsigned)xc < 64u) ? 1.f : 0.f;
    }

    // msk2[2t]   = (row0col0,row0col1) * fold,  msk2[2t+1] = (row1col0,row1col1) * fold
    f32x2 msk2[50];
#pragma unroll
    for (int t = 0; t < 25; t++) {
        float f = vmy[t / 5] * vmx[t % 5];
        unsigned u0 = mrow[(2 * t + 0) * 64];
        unsigned u1 = mrow[(2 * t + 1) * 64];
        f32x2 m01, m23;
        m01.x = bf_lo(u0); m01.y = bf_hi(u0);
        m23.x = bf_lo(u1); m23.y = bf_hi(u1);
        msk2[2 * t + 0] = m01 * f;
        msk2[2 * t + 1] = m23 * f;
    }

    int idxm2 = ((lane - 2) & 63) << 2;
    int idxm1 = ((lane - 1) & 63) << 2;
    int idxp1 = ((lane + 1) & 63) << 2;
    int idxp2 = ((lane + 2) & 63) << 2;

    const float* xbase = x + ((size_t)(n * CI + c0)) * 4096 + lane;
    float*       obase = out + ((size_t)(n * CI + c0) * 128 + 2 * h) * 128 + 2 * lane;

    float ra[5], rb[5];
    unsigned pk[5];
#pragma unroll
    for (int d = 0; d < 5; d++) {
        ra[d] = xbase[yy[d]];
        rb[d] = xbase[4096 + yy[d]];
        pk[d] = cvt_pk_bf16(ra[d], rb[d]);
    }

    for (int p = 0; p < 8; p++) {
        const float* xn = xbase + (size_t)((p < 7) ? (2 * p + 2) : 0) * 4096;
        float na[5], nb[5];
#pragma unroll
        for (int d = 0; d < 5; d++) {
            na[d] = xn[yy[d]];
            nb[d] = xn[4096 + yy[d]];
        }

        f32x2 A0 = {0.f, 0.f}, A1 = {0.f, 0.f};   // rows 0,1 for channel A (cols packed)
        f32x2 B0 = {0.f, 0.f}, B1 = {0.f, 0.f};   // rows 0,1 for channel B
#pragma unroll
        for (int d = 0; d < 5; d++) {
            int pv = (int)pk[d];
            int sm2 = __builtin_amdgcn_ds_bpermute(idxm2, pv);
            int sm1 = __builtin_amdgcn_ds_bpermute(idxm1, pv);
            int sp1 = __builtin_amdgcn_ds_bpermute(idxp1, pv);
            int sp2 = __builtin_amdgcn_ds_bpermute(idxp2, pv);
            f32x2 s[5];
            s[0].x = bf_lo((unsigned)sm2); s[0].y = bf_hi((unsigned)sm2);
            s[1].x = bf_lo((unsigned)sm1); s[1].y = bf_hi((unsigned)sm1);
            s[2].x = ra[d];                s[2].y = rb[d];
            s[3].x = bf_lo((unsigned)sp1); s[3].y = bf_hi((unsigned)sp1);
            s[4].x = bf_lo((unsigned)sp2); s[4].y = bf_hi((unsigned)sp2);
            const f32x2* mk2 = msk2 + d * 10;
#pragma unroll
            for (int k = 0; k < 5; k++) {
                pk_fma_lo(A0, mk2[2 * k + 0], s[k]);   // chA: rows 0
                pk_fma_lo(A1, mk2[2 * k + 1], s[k]);   // chA: rows 1
                pk_fma_hi(B0, mk2[2 * k + 0], s[k]);   // chB: rows 0
                pk_fma_hi(B1, mk2[2 * k + 1], s[k]);   // chB: rows 1
            }
        }
        float* opa = obase + (size_t)(2 * p) * 16384;
        float* opb = opa + 16384;
        nt_store2(opa, A0);
        nt_store2(opa + 128, A1);
        nt_store2(opb, B0);
        nt_store2(opb + 128, B1);

#pragma unroll
        for (int d = 0; d < 5; d++) {
            ra[d] = na[d];
            rb[d] = nb[d];
            pk[d] = cvt_pk_bf16(na[d], nb[d]);
        }
    }
}

extern "C" void kernel_launch(void* const* d_in, const int* in_sizes, int n_in,
                              void* d_out, int out_size, void* d_ws, size_t ws_size,
                              hipStream_t stream) {
    const float* x      = (const float*)d_in[0];
    const float* w_comp = (const float*)d_in[1];
    const float* b_comp = (const float*)d_in[2];
    const float* w_enc  = (const float*)d_in[3];
    const float* b_enc  = (const float*)d_in[4];
    float* out = (float*)d_out;

    // workspace layout (bytes)
    char* ws = (char*)d_ws;
    float*          zp    = (float*)(ws + 0);                 // 256 B zeros
    unsigned short* wA    = (unsigned short*)(ws + 256);      // 32768 B
    unsigned short* Bp    = (unsigned short*)(ws + 33024);    // 129024 B
    unsigned short* comp  = (unsigned short*)(ws + 162048);   // 4 MB
    unsigned*       maskP = (unsigned*)(ws + 4356352);        // 6.55 MB
    // total ~11 MB

    prep_small<<<64, 256, 0, stream>>>(w_comp, wA, zp);
    conv1x1_mfma<<<2048 + 1008, 64, 0, stream>>>(x, wA, b_comp, w_enc, comp, Bp);
    conv3x3_mfma<<<512, 256, 0, stream>>>(comp, Bp, b_enc, zp, maskP);
    reassemble<<<2048, 256, 0, stream>>>(x, maskP, out);
}